// Round 9
// baseline (219.879 us; speedup 1.0000x reference)
//
#include <hip/hip_runtime.h>
#include <hip/hip_bf16.h>

#define Bb 2
#define Tt 2048
#define Cc 1024
#define Hh 16
#define Dd 64

typedef __bf16 bf8 __attribute__((ext_vector_type(8)));
typedef __bf16 bf4 __attribute__((ext_vector_type(4)));
typedef float f4 __attribute__((ext_vector_type(4)));

typedef __attribute__((address_space(3))) void lds_void;
typedef const __attribute__((address_space(1))) void g_void;

__device__ __forceinline__ void gload_lds16(const __bf16* g, __bf16* l) {
  __builtin_amdgcn_global_load_lds((g_void*)g, (lds_void*)l, 16, 0, 0);
}

// exp2 that lowers directly to v_exp_f32 (hw exp is base-2)
__device__ __forceinline__ float ex2(float x) { return __builtin_amdgcn_exp2f(x); }

// fused fp32 -> bf16 convert for x, W_qkv, W_proj in one launch
__global__ __launch_bounds__(256) void cvt3_kernel(
    const float* __restrict__ a, __bf16* __restrict__ oa, int na,
    const float* __restrict__ b, __bf16* __restrict__ ob, int nb,
    const float* __restrict__ c, __bf16* __restrict__ oc) {
  int gi = blockIdx.x * 256 + threadIdx.x;
  const int t0 = na >> 3, t1 = t0 + (nb >> 3);
  const float* src; __bf16* dst; int idx;
  if (gi < t0)      { src = a; dst = oa; idx = gi; }
  else if (gi < t1) { src = b; dst = ob; idx = gi - t0; }
  else              { src = c; dst = oc; idx = gi - t1; }
  const float* p = src + (size_t)idx * 8;
  float4 u = *(const float4*)p;
  float4 v = *(const float4*)(p + 4);
  bf8 r;
  r[0] = (__bf16)u.x; r[1] = (__bf16)u.y; r[2] = (__bf16)u.z; r[3] = (__bf16)u.w;
  r[4] = (__bf16)v.x; r[5] = (__bf16)v.y; r[6] = (__bf16)v.z; r[7] = (__bf16)v.w;
  *(bf8*)(dst + (size_t)idx * 8) = r;
}

// C(M,N) = A(M,K) @ W(N,K)^T + bias.  EXACT R6 structure (proven 50.6 us on
// QKV): single-buffer K-loop (TLP hides latency), ascending-granule staging
// (global_load_lds quads MUST read contiguous 64 B — the R7/R8 XOR swizzle
// permuted quad lanes and cost ~20 us/launch in DMA request fragmentation),
// unswizzled b128 fragment reads (the ~3.1M 4-way conflict cycles are cheaper
// than breaking DMA coalescing).
// MODE 0 (BM=128): scatter q/k (B,H,T,D) + v transposed (B,H,D,T), bf16;
//                  q pre-scaled by 0.125*log2e.
// MODE 1 (BM=64):  fp32 out (leading dim ldo) + bias.
template<int BM, int MODE>
__global__ __launch_bounds__(256) void gemm_kernel(
    const __bf16* __restrict__ A, const __bf16* __restrict__ W,
    const float* __restrict__ bias, int K,
    __bf16* __restrict__ q_ws, __bf16* __restrict__ k_ws,
    __bf16* __restrict__ v_ws, float* __restrict__ out, int ldo)
{
  constexpr int WM = (BM == 128) ? 64 : 32;
  constexpr int MI = WM / 16;                // 4 or 2
  constexpr int NI = 4;                      // WN = 64

  const int tid = threadIdx.x;
  const int lane = tid & 63, wave = tid >> 6;
  const int lr = lane & 15, lq = lane >> 4;
  const int m_blk = blockIdx.y * BM, n_blk = blockIdx.x * 128;
  const int wm = (wave & 1) * WM, wn = (wave >> 1) * 64;

  __shared__ __align__(16) __bf16 As[BM * 32];   // [row][k] contiguous (DMA layout)
  __shared__ __align__(16) __bf16 Bs[128 * 32];

  const int srow = tid >> 2, scol = (tid & 3) * 8;   // ascending granules!
  const __bf16* ag0 = A + (size_t)(m_blk + srow) * K + scol;
  const __bf16* ag1 = ag0 + (size_t)64 * K;          // used only when BM==128
  const __bf16* bg0 = W + (size_t)(n_blk + srow) * K + scol;
  const __bf16* bg1 = bg0 + (size_t)64 * K;
  __bf16* al0 = As + tid * 8;          // byte off = tid*16 (wave-uniform + lane*16)
  __bf16* al1 = As + 2048 + tid * 8;
  __bf16* bl0 = Bs + tid * 8;
  __bf16* bl1 = Bs + 2048 + tid * 8;

  f4 acc[MI][NI] = {};
  for (int k0 = 0; k0 < K; k0 += 32) {
    gload_lds16(ag0 + k0, al0);
    if constexpr (BM == 128) gload_lds16(ag1 + k0, al1);
    gload_lds16(bg0 + k0, bl0);
    gload_lds16(bg1 + k0, bl1);
    __syncthreads();   // drains DMA (vmcnt) before reads

    bf8 af[MI], bfr[NI];
    #pragma unroll
    for (int i = 0; i < MI; ++i)
      af[i] = *(const bf8*)&As[(wm + i * 16 + lr) * 32 + lq * 8];
    #pragma unroll
    for (int j = 0; j < NI; ++j)
      bfr[j] = *(const bf8*)&Bs[(wn + j * 16 + lr) * 32 + lq * 8];
    #pragma unroll
    for (int i = 0; i < MI; ++i)
      #pragma unroll
      for (int j = 0; j < NI; ++j)
        acc[i][j] = __builtin_amdgcn_mfma_f32_16x16x32_bf16(af[i], bfr[j], acc[i][j], 0, 0, 0);
    __syncthreads();   // LDS reads done before next-iter staging overwrites
  }

  #pragma unroll
  for (int i = 0; i < MI; ++i) {
    #pragma unroll
    for (int j = 0; j < NI; ++j) {
      #pragma unroll
      for (int r = 0; r < 4; ++r) {
        int row = m_blk + wm + i * 16 + lq * 4 + r;  // C/D: row = 4*quad + reg
        int col = n_blk + wn + j * 16 + lr;          // C/D: col = lane&15
        float val = acc[i][j][r] + bias[col];
        if constexpr (MODE == 0) {
          int which = col >> 10, rr = col & 1023;
          int h = rr >> 6, d = rr & 63;
          int b = row >> 11, t = row & 2047;
          if (which == 0) val *= 0.18033688011112042f;  // 1/sqrt(D) * log2(e)
          __bf16 bv = (__bf16)val;
          size_t bh = (size_t)b * Hh + h;
          if (which == 0)      q_ws[(bh * Tt + t) * Dd + d] = bv;
          else if (which == 1) k_ws[(bh * Tt + t) * Dd + d] = bv;
          else                 v_ws[(bh * Dd + d) * Tt + t] = bv;
        } else {
          out[(size_t)row * ldo + col] = val;
        }
      }
    }
  }
}

// Flash attention with sink, fixed softmax reference m=0, log2-domain scores
// (q pre-scaled by 0.125*log2e -> exp is a bare v_exp_f32). S computed
// TRANSPOSED (A=K, B=Q); P spills as b64, reads back as b128 A-frags.
// Software pipeline: triple-buffered K/V ring; during iter kt the wave
// computes S(kt+1) (K-tile already drained at this barrier) so S-MFMA(kt+1)
// co-issues with the exp-VALU(kt) block -> MFMA/VALU overlap within a wave.
// Grid: 512 blocks; i and i+256 have qt summing to 15 (balanced pairs).
__global__ __launch_bounds__(256) void attn_kernel(
    const __bf16* __restrict__ q_ws, const __bf16* __restrict__ k_ws,
    const __bf16* __restrict__ v_ws, const float* __restrict__ sink,
    __bf16* __restrict__ y_ws)
{
  int bi = blockIdx.x;
  int qt, bhi;
  if (bi < 256) { qt = 15 - (bi >> 5); bhi = bi & 31; }
  else          { qt = (bi - 256) >> 5; bhi = (bi - 256) & 31; }
  const int h = bhi & (Hh - 1);
  const int b = bhi >> 4;
  const int tid = threadIdx.x;
  const int lane = tid & 63, wave = tid >> 6;
  const int lr = lane & 15, lq = lane >> 4;

  __shared__ __align__(16) __bf16 KsU[3][64 * 64];     // swizzled [key][d], ring
  __shared__ __align__(16) __bf16 VtU[3][64 * 64];     // swizzled [d][key], ring
  __shared__ __align__(16) __bf16 PsU[4][2 * 16 * 64]; // per-wave [qs][q][key]

  const __bf16* qp = q_ws + (size_t)bhi * Tt * Dd;
  const __bf16* kp = k_ws + (size_t)bhi * Tt * Dd;
  const __bf16* vp = v_ws + (size_t)bhi * Dd * Tt;     // [d][t]

  const int qbase = qt * 128;
  const int qlo = qbase + wave * 32;                   // wave's lowest q row

  // Q fragments: 2 subsets of 16 rows/wave, loop-invariant registers
  bf8 qf[2][2];
  #pragma unroll
  for (int qs = 0; qs < 2; ++qs) {
    const __bf16* qrow = qp + (size_t)(qlo + qs * 16 + lr) * Dd;
    qf[qs][0] = *(const bf8*)(qrow + lq * 8);
    qf[qs][1] = *(const bf8*)(qrow + 32 + lq * 8);
  }

  float rs[2] = {0.f, 0.f};   // per-lane denominator partial (q = lr, per subset)
  f4 o_acc[2][4] = {};

  const int srow_lo = wave * 8 + (lane >> 3);
  const int sslot = lane & 7;
  const int nkt = 2 * qt + 2;

  auto stage = [&](int kt2, int bsel) {
    const int kbase2 = kt2 * 64;
    #pragma unroll
    for (int ii = 0; ii < 2; ++ii) {
      const int r = ii * 32 + srow_lo;
      const int cc = sslot ^ (r & 7);            // XOR granule swizzle
      gload_lds16(kp + (size_t)(kbase2 + r) * Dd + cc * 8,
                  &KsU[bsel][ii * 2048 + wave * 512 + lane * 8]);
      gload_lds16(vp + (size_t)r * Tt + kbase2 + cc * 8,
                  &VtU[bsel][ii * 2048 + wave * 512 + lane * 8]);
    }
  };

  auto computeS = [&](const __bf16* Kb, f4 (&sA)[4][2]) {
    #pragma unroll
    for (int nt = 0; nt < 4; ++nt) {
      const int krow = nt * 16 + lr;
      const int x7 = krow & 7;
      bf8 kb0 = *(const bf8*)&Kb[krow * 64 + ((lq ^ x7) * 8)];
      bf8 kb1 = *(const bf8*)&Kb[krow * 64 + (((4 + lq) ^ x7) * 8)];
      #pragma unroll
      for (int qs = 0; qs < 2; ++qs) {
        f4 c = {};
        c = __builtin_amdgcn_mfma_f32_16x16x32_bf16(kb0, qf[qs][0], c, 0, 0, 0);
        c = __builtin_amdgcn_mfma_f32_16x16x32_bf16(kb1, qf[qs][1], c, 0, 0, 0);
        sA[nt][qs] = c;
      }
    }
  };

  f4 s_cur[4][2], s_next[4][2];

  stage(0, 0);
  __syncthreads();          // drain DMA(0)
  stage(1, 1);              // drains at first loop barrier
  computeS(KsU[0], s_cur);

  for (int kt = 0; kt < nkt; ++kt) {
    __syncthreads();        // drains DMA(kt+1); syncs ring reuse
    if (kt + 2 < nkt) stage(kt + 2, (kt + 2) % 3);

    // prefetch S for next tile — independent of exp/PV below (MFMA ∥ VALU)
    if (kt + 1 < nkt && (kt + 1) * 64 <= qlo + 31)
      computeS(KsU[(kt + 1) % 3], s_next);

    const int kbase = kt * 64;
    if (kbase <= qlo + 31) {
      __bf16* Pw = PsU[wave];
      const bool diag = (kbase + 63 > qlo);   // wave-uniform
      if (diag) {
        #pragma unroll
        for (int nt = 0; nt < 4; ++nt)
          #pragma unroll
          for (int qs = 0; qs < 2; ++qs) {
            const int qg = qlo + qs * 16 + lr;
            const int kg = kbase + nt * 16 + lq * 4;
            bf4 pb;
            #pragma unroll
            for (int r = 0; r < 4; ++r) {
              float sv = (kg + r > qg) ? -1e30f : s_cur[nt][qs][r];
              float p = ex2(sv);              // scores already in log2 domain
              rs[qs] += p;
              pb[r] = (__bf16)p;
            }
            const int G = (nt * 2 + (lq >> 1)) ^ (lr & 7);
            *(bf4*)&Pw[(qs * 16 + lr) * 64 + G * 8 + (lq & 1) * 4] = pb;
          }
      } else {
        #pragma unroll
        for (int nt = 0; nt < 4; ++nt)
          #pragma unroll
          for (int qs = 0; qs < 2; ++qs) {
            bf4 pb;
            #pragma unroll
            for (int r = 0; r < 4; ++r) {
              float p = ex2(s_cur[nt][qs][r]);
              rs[qs] += p;
              pb[r] = (__bf16)p;
            }
            const int G = (nt * 2 + (lq >> 1)) ^ (lr & 7);
            *(bf4*)&Pw[(qs * 16 + lr) * 64 + G * 8 + (lq & 1) * 4] = pb;
          }
      }
      asm volatile("s_waitcnt lgkmcnt(0)" ::: "memory");  // wave-private RAW on Pw

      const __bf16* Vb = VtU[kt % 3];
      #pragma unroll
      for (int ks = 0; ks < 2; ++ks) {
        const int pg = ((ks * 4 + lq) ^ (lr & 7)) * 8;
        bf8 pa0 = *(const bf8*)&Pw[lr * 64 + pg];
        bf8 pa1 = *(const bf8*)&Pw[(16 + lr) * 64 + pg];
        #pragma unroll
        for (int dt = 0; dt < 4; ++dt) {
          const int vrow = dt * 16 + lr;
          bf8 vb = *(const bf8*)&Vb[vrow * 64 + (((ks * 4 + lq) ^ (vrow & 7)) * 8)];
          o_acc[0][dt] = __builtin_amdgcn_mfma_f32_16x16x32_bf16(pa0, vb, o_acc[0][dt], 0, 0, 0);
          o_acc[1][dt] = __builtin_amdgcn_mfma_f32_16x16x32_bf16(pa1, vb, o_acc[1][dt], 0, 0, 0);
        }
      }
    }

    #pragma unroll
    for (int nt = 0; nt < 4; ++nt)
      #pragma unroll
      for (int qs = 0; qs < 2; ++qs)
        s_cur[nt][qs] = s_next[nt][qs];
  }

  // denominator: reduce per-lane partials over lq (lanes sharing lr)
  #pragma unroll
  for (int qs = 0; qs < 2; ++qs) {
    rs[qs] += __shfl_xor(rs[qs], 16, 64);
    rs[qs] += __shfl_xor(rs[qs], 32, 64);
  }
  const float snk = ex2(sink[h] * 1.44269504f);   // e^sink
  float inv0 = 1.0f / (rs[0] + snk);
  float inv1 = 1.0f / (rs[1] + snk);
  // redistribute: O rows are q = lq*4+r; denom lives at lane with lr == lq*4+r
  float invr[2][4];
  #pragma unroll
  for (int r = 0; r < 4; ++r) {
    invr[0][r] = __shfl(inv0, lq * 4 + r, 64);
    invr[1][r] = __shfl(inv1, lq * 4 + r, 64);
  }

  #pragma unroll
  for (int qs = 0; qs < 2; ++qs)
    #pragma unroll
    for (int dt = 0; dt < 4; ++dt)
      #pragma unroll
      for (int r = 0; r < 4; ++r) {
        int qrow = qbase + wave * 32 + qs * 16 + lq * 4 + r;
        y_ws[((size_t)b * Tt + qrow) * Cc + h * Dd + dt * 16 + lr] =
            (__bf16)(o_acc[qs][dt][r] * invr[qs][r]);
      }
}

extern "C" void kernel_launch(void* const* d_in, const int* in_sizes, int n_in,
                              void* d_out, int out_size, void* d_ws, size_t ws_size,
                              hipStream_t stream) {
  const float* x      = (const float*)d_in[0];
  const float* W_qkv  = (const float*)d_in[1];
  const float* b_qkv  = (const float*)d_in[2];
  const float* W_proj = (const float*)d_in[3];
  const float* b_proj = (const float*)d_in[4];
  const float* sinkp  = (const float*)d_in[5];
  float* out = (float*)d_out;

  const size_t n_x    = (size_t)Bb * Tt * Cc;        // 4.19M
  const size_t n_wqkv = (size_t)3 * Hh * Dd * Cc;    // 3.15M
  const size_t n_wprj = (size_t)Cc * Hh * Dd;        // 1.05M
  const size_t nqkv   = (size_t)Bb * Hh * Tt * Dd;   // 4.19M

  __bf16* xb     = (__bf16*)d_ws;          // also aliased as y_ws after QKV GEMM
  __bf16* wqkvb  = xb + n_x;
  __bf16* wprojb = wqkvb + n_wqkv;
  __bf16* q_ws   = wprojb + n_wprj;
  __bf16* k_ws   = q_ws + nqkv;
  __bf16* v_ws   = k_ws + nqkv;
  __bf16* y_ws   = xb;                     // lifetime-disjoint alias

  dim3 blk(256);
  const int cvt_blocks = (int)((n_x + n_wqkv + n_wprj) / 8 / 256);  // 4096
  cvt3_kernel<<<cvt_blocks, blk, 0, stream>>>(x, xb, (int)n_x,
                                              W_qkv, wqkvb, (int)n_wqkv,
                                              W_proj, wprojb);

  // QKV: M=4096, N=3072, K=1024 — 768 blocks (3/CU), 16 KB LDS (R6 structure)
  gemm_kernel<128, 0><<<dim3(3 * Cc / 128, Bb * Tt / 128), blk, 0, stream>>>(
      xb, wqkvb, b_qkv, Cc, q_ws, k_ws, v_ws, nullptr, 0);
  // attention: 512 balanced-pair blocks (2/CU)
  attn_kernel<<<dim3(512), blk, 0, stream>>>(q_ws, k_ws, v_ws, sinkp, y_ws);
  // proj: M=4096, N=1024, K=1024 — 64-row tiles -> 512 blocks (2/CU), 12 KB LDS
  gemm_kernel<64, 1><<<dim3(Cc / 128, Bb * Tt / 64), blk, 0, stream>>>(
      y_ws, wprojb, b_proj, Hh * Dd, nullptr, nullptr, nullptr, out, Cc);
}

// Round 10
// 203.329 us; speedup vs baseline: 1.0814x; 1.0814x over previous
//
#include <hip/hip_runtime.h>
#include <hip/hip_bf16.h>

#define Bb 2
#define Tt 2048
#define Cc 1024
#define Hh 16
#define Dd 64

typedef __bf16 bf8 __attribute__((ext_vector_type(8)));
typedef __bf16 bf4 __attribute__((ext_vector_type(4)));
typedef float f4 __attribute__((ext_vector_type(4)));

typedef __attribute__((address_space(3))) void lds_void;
typedef const __attribute__((address_space(1))) void g_void;

__device__ __forceinline__ void gload_lds16(const __bf16* g, __bf16* l) {
  __builtin_amdgcn_global_load_lds((g_void*)g, (lds_void*)l, 16, 0, 0);
}

// exp2 that lowers directly to v_exp_f32 (hw exp is base-2)
__device__ __forceinline__ float ex2(float x) { return __builtin_amdgcn_exp2f(x); }

// fused fp32 -> bf16 convert for x, W_qkv, W_proj in one launch
__global__ __launch_bounds__(256) void cvt3_kernel(
    const float* __restrict__ a, __bf16* __restrict__ oa, int na,
    const float* __restrict__ b, __bf16* __restrict__ ob, int nb,
    const float* __restrict__ c, __bf16* __restrict__ oc) {
  int gi = blockIdx.x * 256 + threadIdx.x;
  const int t0 = na >> 3, t1 = t0 + (nb >> 3);
  const float* src; __bf16* dst; int idx;
  if (gi < t0)      { src = a; dst = oa; idx = gi; }
  else if (gi < t1) { src = b; dst = ob; idx = gi - t0; }
  else              { src = c; dst = oc; idx = gi - t1; }
  const float* p = src + (size_t)idx * 8;
  float4 u = *(const float4*)p;
  float4 v = *(const float4*)(p + 4);
  bf8 r;
  r[0] = (__bf16)u.x; r[1] = (__bf16)u.y; r[2] = (__bf16)u.z; r[3] = (__bf16)u.w;
  r[4] = (__bf16)v.x; r[5] = (__bf16)v.y; r[6] = (__bf16)v.z; r[7] = (__bf16)v.w;
  *(bf8*)(dst + (size_t)idx * 8) = r;
}

// C(M,N) = A(M,K) @ W(N,K)^T + bias   — m97 structure: 128x128 tile, BK=32,
// global_load_lds width-16 staging, ds_read_b128 fragments, 4x4 acc/wave.
// (ANCHOR: this exact kernel measured 50.6 us on QKV in R6. R7-R9 variants
// measured 66-73 us but cross-session drift confounded those comparisons —
// only within-round counter deltas are trustworthy.)
// mode 0: scatter into q_ws/k_ws (B,H,T,D) and v_ws (B,H,D,T), bf16
//         (q is pre-scaled by 0.125*log2(e) so attention exp is a bare v_exp_f32)
// mode 1: fp32 out (row-major, leading dim ldo) + bias
__global__ __launch_bounds__(256) void gemm128_kernel(
    const __bf16* __restrict__ A, const __bf16* __restrict__ W,
    const float* __restrict__ bias, int K, int mode,
    __bf16* __restrict__ q_ws, __bf16* __restrict__ k_ws,
    __bf16* __restrict__ v_ws, float* __restrict__ out, int ldo)
{
  const int tid = threadIdx.x;
  const int lane = tid & 63, wave = tid >> 6;
  const int lr = lane & 15, lq = lane >> 4;
  const int m_blk = blockIdx.y * 128, n_blk = blockIdx.x * 128;
  const int wm = (wave & 1) * 64, wn = (wave >> 1) * 64;

  __shared__ __align__(16) __bf16 As[128 * 32];  // [row][k] contiguous (no pad: global_load_lds)
  __shared__ __align__(16) __bf16 Bs[128 * 32];

  const int srow = tid >> 2, scol = (tid & 3) * 8;
  const __bf16* ag0 = A + (size_t)(m_blk + srow) * K + scol;
  const __bf16* ag1 = A + (size_t)(m_blk + 64 + srow) * K + scol;
  const __bf16* bg0 = W + (size_t)(n_blk + srow) * K + scol;
  const __bf16* bg1 = W + (size_t)(n_blk + 64 + srow) * K + scol;
  __bf16* al0 = As + tid * 8;          // byte off = tid*16 (wave-uniform base + lane*16)
  __bf16* al1 = As + 2048 + tid * 8;
  __bf16* bl0 = Bs + tid * 8;
  __bf16* bl1 = Bs + 2048 + tid * 8;

  f4 acc[4][4] = {};
  for (int k0 = 0; k0 < K; k0 += 32) {
    gload_lds16(ag0 + k0, al0);
    gload_lds16(ag1 + k0, al1);
    gload_lds16(bg0 + k0, bl0);
    gload_lds16(bg1 + k0, bl1);
    __syncthreads();   // drains vmcnt (global_load_lds) before reads

    bf8 af[4], bfr[4];
    #pragma unroll
    for (int i = 0; i < 4; ++i)
      af[i] = *(const bf8*)&As[(wm + i * 16 + lr) * 32 + lq * 8];
    #pragma unroll
    for (int j = 0; j < 4; ++j)
      bfr[j] = *(const bf8*)&Bs[(wn + j * 16 + lr) * 32 + lq * 8];
    #pragma unroll
    for (int i = 0; i < 4; ++i)
      #pragma unroll
      for (int j = 0; j < 4; ++j)
        acc[i][j] = __builtin_amdgcn_mfma_f32_16x16x32_bf16(af[i], bfr[j], acc[i][j], 0, 0, 0);
    __syncthreads();   // LDS reads done before next-iter staging overwrites
  }

  #pragma unroll
  for (int i = 0; i < 4; ++i) {
    #pragma unroll
    for (int j = 0; j < 4; ++j) {
      #pragma unroll
      for (int r = 0; r < 4; ++r) {
        int row = m_blk + wm + i * 16 + lq * 4 + r;  // C/D: row = 4*quad + reg
        int col = n_blk + wn + j * 16 + lr;          // C/D: col = lane&15
        float val = acc[i][j][r] + bias[col];
        if (mode == 0) {
          int which = col >> 10, rr = col & 1023;
          int h = rr >> 6, d = rr & 63;
          int b = row >> 11, t = row & 2047;
          if (which == 0) val *= 0.18033688011112042f;  // 1/sqrt(D) * log2(e)
          __bf16 bv = (__bf16)val;
          size_t bh = (size_t)b * Hh + h;
          if (which == 0)      q_ws[(bh * Tt + t) * Dd + d] = bv;
          else if (which == 1) k_ws[(bh * Tt + t) * Dd + d] = bv;
          else                 v_ws[(bh * Dd + d) * Tt + t] = bv;
        } else {
          out[(size_t)row * ldo + col] = val;
        }
      }
    }
  }
}

// Flash attention with sink, fixed softmax reference m=0, log2-domain scores
// (q pre-scaled by 0.125*log2e -> exp is a bare v_exp_f32). S computed
// TRANSPOSED (A=K, B=Q); P spills as b64, reads back as b128 A-frags.
// Software pipeline: triple-buffered K/V ring; during iter kt the wave
// computes S(kt+1) (K-tile already drained at this barrier) so S-MFMA(kt+1)
// co-issues with the exp-VALU(kt) block -> MFMA/VALU overlap within a wave.
// Grid: 512 blocks; i and i+256 have qt summing to 15 (balanced pairs).
__global__ __launch_bounds__(256) void attn_kernel(
    const __bf16* __restrict__ q_ws, const __bf16* __restrict__ k_ws,
    const __bf16* __restrict__ v_ws, const float* __restrict__ sink,
    __bf16* __restrict__ y_ws)
{
  int bi = blockIdx.x;
  int qt, bhi;
  if (bi < 256) { qt = 15 - (bi >> 5); bhi = bi & 31; }
  else          { qt = (bi - 256) >> 5; bhi = (bi - 256) & 31; }
  const int h = bhi & (Hh - 1);
  const int b = bhi >> 4;
  const int tid = threadIdx.x;
  const int lane = tid & 63, wave = tid >> 6;
  const int lr = lane & 15, lq = lane >> 4;

  __shared__ __align__(16) __bf16 KsU[3][64 * 64];     // swizzled [key][d], ring
  __shared__ __align__(16) __bf16 VtU[3][64 * 64];     // swizzled [d][key], ring
  __shared__ __align__(16) __bf16 PsU[4][2 * 16 * 64]; // per-wave [qs][q][key]

  const __bf16* qp = q_ws + (size_t)bhi * Tt * Dd;
  const __bf16* kp = k_ws + (size_t)bhi * Tt * Dd;
  const __bf16* vp = v_ws + (size_t)bhi * Dd * Tt;     // [d][t]

  const int qbase = qt * 128;
  const int qlo = qbase + wave * 32;                   // wave's lowest q row

  // Q fragments: 2 subsets of 16 rows/wave, loop-invariant registers
  bf8 qf[2][2];
  #pragma unroll
  for (int qs = 0; qs < 2; ++qs) {
    const __bf16* qrow = qp + (size_t)(qlo + qs * 16 + lr) * Dd;
    qf[qs][0] = *(const bf8*)(qrow + lq * 8);
    qf[qs][1] = *(const bf8*)(qrow + 32 + lq * 8);
  }

  float rs[2] = {0.f, 0.f};   // per-lane denominator partial (q = lr, per subset)
  f4 o_acc[2][4] = {};

  const int srow_lo = wave * 8 + (lane >> 3);
  const int sslot = lane & 7;
  const int nkt = 2 * qt + 2;

  auto stage = [&](int kt2, int bsel) {
    const int kbase2 = kt2 * 64;
    #pragma unroll
    for (int ii = 0; ii < 2; ++ii) {
      const int r = ii * 32 + srow_lo;
      const int cc = sslot ^ (r & 7);            // XOR granule swizzle
      gload_lds16(kp + (size_t)(kbase2 + r) * Dd + cc * 8,
                  &KsU[bsel][ii * 2048 + wave * 512 + lane * 8]);
      gload_lds16(vp + (size_t)r * Tt + kbase2 + cc * 8,
                  &VtU[bsel][ii * 2048 + wave * 512 + lane * 8]);
    }
  };

  auto computeS = [&](const __bf16* Kb, f4 (&sA)[4][2]) {
    #pragma unroll
    for (int nt = 0; nt < 4; ++nt) {
      const int krow = nt * 16 + lr;
      const int x7 = krow & 7;
      bf8 kb0 = *(const bf8*)&Kb[krow * 64 + ((lq ^ x7) * 8)];
      bf8 kb1 = *(const bf8*)&Kb[krow * 64 + (((4 + lq) ^ x7) * 8)];
      #pragma unroll
      for (int qs = 0; qs < 2; ++qs) {
        f4 c = {};
        c = __builtin_amdgcn_mfma_f32_16x16x32_bf16(kb0, qf[qs][0], c, 0, 0, 0);
        c = __builtin_amdgcn_mfma_f32_16x16x32_bf16(kb1, qf[qs][1], c, 0, 0, 0);
        sA[nt][qs] = c;
      }
    }
  };

  f4 s_cur[4][2], s_next[4][2];

  stage(0, 0);
  __syncthreads();          // drain DMA(0)
  stage(1, 1);              // drains at first loop barrier
  computeS(KsU[0], s_cur);

  for (int kt = 0; kt < nkt; ++kt) {
    __syncthreads();        // drains DMA(kt+1); syncs ring reuse
    if (kt + 2 < nkt) stage(kt + 2, (kt + 2) % 3);

    // prefetch S for next tile — independent of exp/PV below (MFMA ∥ VALU)
    if (kt + 1 < nkt && (kt + 1) * 64 <= qlo + 31)
      computeS(KsU[(kt + 1) % 3], s_next);

    const int kbase = kt * 64;
    if (kbase <= qlo + 31) {
      __bf16* Pw = PsU[wave];
      const bool diag = (kbase + 63 > qlo);   // wave-uniform
      if (diag) {
        #pragma unroll
        for (int nt = 0; nt < 4; ++nt)
          #pragma unroll
          for (int qs = 0; qs < 2; ++qs) {
            const int qg = qlo + qs * 16 + lr;
            const int kg = kbase + nt * 16 + lq * 4;
            bf4 pb;
            #pragma unroll
            for (int r = 0; r < 4; ++r) {
              float sv = (kg + r > qg) ? -1e30f : s_cur[nt][qs][r];
              float p = ex2(sv);              // scores already in log2 domain
              rs[qs] += p;
              pb[r] = (__bf16)p;
            }
            const int G = (nt * 2 + (lq >> 1)) ^ (lr & 7);
            *(bf4*)&Pw[(qs * 16 + lr) * 64 + G * 8 + (lq & 1) * 4] = pb;
          }
      } else {
        #pragma unroll
        for (int nt = 0; nt < 4; ++nt)
          #pragma unroll
          for (int qs = 0; qs < 2; ++qs) {
            bf4 pb;
            #pragma unroll
            for (int r = 0; r < 4; ++r) {
              float p = ex2(s_cur[nt][qs][r]);
              rs[qs] += p;
              pb[r] = (__bf16)p;
            }
            const int G = (nt * 2 + (lq >> 1)) ^ (lr & 7);
            *(bf4*)&Pw[(qs * 16 + lr) * 64 + G * 8 + (lq & 1) * 4] = pb;
          }
      }
      asm volatile("s_waitcnt lgkmcnt(0)" ::: "memory");  // wave-private RAW on Pw

      const __bf16* Vb = VtU[kt % 3];
      #pragma unroll
      for (int ks = 0; ks < 2; ++ks) {
        const int pg = ((ks * 4 + lq) ^ (lr & 7)) * 8;
        bf8 pa0 = *(const bf8*)&Pw[lr * 64 + pg];
        bf8 pa1 = *(const bf8*)&Pw[(16 + lr) * 64 + pg];
        #pragma unroll
        for (int dt = 0; dt < 4; ++dt) {
          const int vrow = dt * 16 + lr;
          bf8 vb = *(const bf8*)&Vb[vrow * 64 + (((ks * 4 + lq) ^ (vrow & 7)) * 8)];
          o_acc[0][dt] = __builtin_amdgcn_mfma_f32_16x16x32_bf16(pa0, vb, o_acc[0][dt], 0, 0, 0);
          o_acc[1][dt] = __builtin_amdgcn_mfma_f32_16x16x32_bf16(pa1, vb, o_acc[1][dt], 0, 0, 0);
        }
      }
    }

    #pragma unroll
    for (int nt = 0; nt < 4; ++nt)
      #pragma unroll
      for (int qs = 0; qs < 2; ++qs)
        s_cur[nt][qs] = s_next[nt][qs];
  }

  // denominator: reduce per-lane partials over lq (lanes sharing lr)
  #pragma unroll
  for (int qs = 0; qs < 2; ++qs) {
    rs[qs] += __shfl_xor(rs[qs], 16, 64);
    rs[qs] += __shfl_xor(rs[qs], 32, 64);
  }
  const float snk = ex2(sink[h] * 1.44269504f);   // e^sink
  float inv0 = 1.0f / (rs[0] + snk);
  float inv1 = 1.0f / (rs[1] + snk);
  // redistribute: O rows are q = lq*4+r; denom lives at lane with lr == lq*4+r
  float invr[2][4];
  #pragma unroll
  for (int r = 0; r < 4; ++r) {
    invr[0][r] = __shfl(inv0, lq * 4 + r, 64);
    invr[1][r] = __shfl(inv1, lq * 4 + r, 64);
  }

  #pragma unroll
  for (int qs = 0; qs < 2; ++qs)
    #pragma unroll
    for (int dt = 0; dt < 4; ++dt)
      #pragma unroll
      for (int r = 0; r < 4; ++r) {
        int qrow = qbase + wave * 32 + qs * 16 + lq * 4 + r;
        y_ws[((size_t)b * Tt + qrow) * Cc + h * Dd + dt * 16 + lr] =
            (__bf16)(o_acc[qs][dt][r] * invr[qs][r]);
      }
}

extern "C" void kernel_launch(void* const* d_in, const int* in_sizes, int n_in,
                              void* d_out, int out_size, void* d_ws, size_t ws_size,
                              hipStream_t stream) {
  const float* x      = (const float*)d_in[0];
  const float* W_qkv  = (const float*)d_in[1];
  const float* b_qkv  = (const float*)d_in[2];
  const float* W_proj = (const float*)d_in[3];
  const float* b_proj = (const float*)d_in[4];
  const float* sinkp  = (const float*)d_in[5];
  float* out = (float*)d_out;

  const size_t n_x    = (size_t)Bb * Tt * Cc;        // 4.19M
  const size_t n_wqkv = (size_t)3 * Hh * Dd * Cc;    // 3.15M
  const size_t n_wprj = (size_t)Cc * Hh * Dd;        // 1.05M
  const size_t nqkv   = (size_t)Bb * Hh * Tt * Dd;   // 4.19M

  __bf16* xb     = (__bf16*)d_ws;          // also aliased as y_ws after QKV GEMM
  __bf16* wqkvb  = xb + n_x;
  __bf16* wprojb = wqkvb + n_wqkv;
  __bf16* q_ws   = wprojb + n_wprj;
  __bf16* k_ws   = q_ws + nqkv;
  __bf16* v_ws   = k_ws + nqkv;
  __bf16* y_ws   = xb;                     // lifetime-disjoint alias

  dim3 blk(256);
  const int cvt_blocks = (int)((n_x + n_wqkv + n_wprj) / 8 / 256);  // 4096
  cvt3_kernel<<<cvt_blocks, blk, 0, stream>>>(x, xb, (int)n_x,
                                              W_qkv, wqkvb, (int)n_wqkv,
                                              W_proj, wprojb);

  // QKV: M=4096, N=3072, K=1024
  gemm128_kernel<<<dim3(3 * Cc / 128, Bb * Tt / 128), blk, 0, stream>>>(
      xb, wqkvb, b_qkv, Cc, 0, q_ws, k_ws, v_ws, nullptr, 0);
  // attention: 512 balanced-pair blocks
  attn_kernel<<<dim3(512), blk, 0, stream>>>(q_ws, k_ws, v_ws, sinkp, y_ws);
  // proj: M=4096, N=1024, K=1024
  gemm128_kernel<<<dim3(Cc / 128, Bb * Tt / 128), blk, 0, stream>>>(
      y_ws, wprojb, b_proj, Hh * Dd, 1, nullptr, nullptr, nullptr, out, Cc);
}

// Round 11
// 202.627 us; speedup vs baseline: 1.0851x; 1.0035x over previous
//
#include <hip/hip_runtime.h>
#include <hip/hip_bf16.h>

#define Bb 2
#define Tt 2048
#define Cc 1024
#define Hh 16
#define Dd 64

typedef __bf16 bf8 __attribute__((ext_vector_type(8)));
typedef __bf16 bf4 __attribute__((ext_vector_type(4)));
typedef float f4 __attribute__((ext_vector_type(4)));
typedef float f16v __attribute__((ext_vector_type(16)));

typedef __attribute__((address_space(3))) void lds_void;
typedef const __attribute__((address_space(1))) void g_void;

__device__ __forceinline__ void gload_lds16(const __bf16* g, __bf16* l) {
  __builtin_amdgcn_global_load_lds((g_void*)g, (lds_void*)l, 16, 0, 0);
}

// exp2 that lowers directly to v_exp_f32 (hw exp is base-2)
__device__ __forceinline__ float ex2(float x) { return __builtin_amdgcn_exp2f(x); }

// fused fp32 -> bf16 convert for x, W_qkv, W_proj in one launch
__global__ __launch_bounds__(256) void cvt3_kernel(
    const float* __restrict__ a, __bf16* __restrict__ oa, int na,
    const float* __restrict__ b, __bf16* __restrict__ ob, int nb,
    const float* __restrict__ c, __bf16* __restrict__ oc) {
  int gi = blockIdx.x * 256 + threadIdx.x;
  const int t0 = na >> 3, t1 = t0 + (nb >> 3);
  const float* src; __bf16* dst; int idx;
  if (gi < t0)      { src = a; dst = oa; idx = gi; }
  else if (gi < t1) { src = b; dst = ob; idx = gi - t0; }
  else              { src = c; dst = oc; idx = gi - t1; }
  const float* p = src + (size_t)idx * 8;
  float4 u = *(const float4*)p;
  float4 v = *(const float4*)(p + 4);
  bf8 r;
  r[0] = (__bf16)u.x; r[1] = (__bf16)u.y; r[2] = (__bf16)u.z; r[3] = (__bf16)u.w;
  r[4] = (__bf16)v.x; r[5] = (__bf16)v.y; r[6] = (__bf16)v.z; r[7] = (__bf16)v.w;
  *(bf8*)(dst + (size_t)idx * 8) = r;
}

// C(M,N) = A(M,K) @ W(N,K)^T + bias — 128x128 tile, BK=32, contiguous
// global_load_lds staging (NO swizzle — anchor-proven), double-buffered
// (stage(k+1) issued right after the barrier that drains stage(k), so each
// DMA gets a full compute window), mfma_32x32x16 (8 MFMA + 8 ds_read_b128
// per K=32 vs 16+8 with 16x16x32; ~17% fewer matrix-pipe cycles per m06/m119).
// A/B frag: m=lane&31, k=8*(lane>>5)+j.  C/D: col=lane&31,
// row=(reg&3)+8*(reg>>2)+4*(lane>>5)  [HW-verified m74/m101].
// mode 0: scatter q/k (B,H,T,D) + v transposed (B,H,D,T), bf16;
//         q pre-scaled by 0.125*log2(e).
// mode 1: fp32 out (row-major, leading dim ldo) + bias.
__global__ __launch_bounds__(256) void gemm128_kernel(
    const __bf16* __restrict__ A, const __bf16* __restrict__ W,
    const float* __restrict__ bias, int K, int mode,
    __bf16* __restrict__ q_ws, __bf16* __restrict__ k_ws,
    __bf16* __restrict__ v_ws, float* __restrict__ out, int ldo)
{
  const int tid = threadIdx.x;
  const int lane = tid & 63, wave = tid >> 6;
  const int l32 = lane & 31, lh = lane >> 5;
  const int m_blk = blockIdx.y * 128, n_blk = blockIdx.x * 128;
  const int wm = (wave & 1) * 64, wn = (wave >> 1) * 64;

  __shared__ __align__(16) __bf16 As[2][128 * 32];  // [row][k] contiguous (DMA layout)
  __shared__ __align__(16) __bf16 Bs[2][128 * 32];

  const int srow = tid >> 2, scol = (tid & 3) * 8;   // ascending granules
  const __bf16* ag0 = A + (size_t)(m_blk + srow) * K + scol;
  const __bf16* ag1 = ag0 + (size_t)64 * K;
  const __bf16* bg0 = W + (size_t)(n_blk + srow) * K + scol;
  const __bf16* bg1 = bg0 + (size_t)64 * K;

  auto stage = [&](int k0, int bsel) {
    gload_lds16(ag0 + k0, &As[bsel][tid * 8]);
    gload_lds16(ag1 + k0, &As[bsel][2048 + tid * 8]);
    gload_lds16(bg0 + k0, &Bs[bsel][tid * 8]);
    gload_lds16(bg1 + k0, &Bs[bsel][2048 + tid * 8]);
  };

  f16v acc[2][2] = {};

  auto compute = [&](const __bf16* Ab, const __bf16* Bw) {
    #pragma unroll
    for (int ks = 0; ks < 2; ++ks) {          // two K=16 steps per BK=32
      bf8 af[2], bfr[2];
      #pragma unroll
      for (int mt = 0; mt < 2; ++mt)
        af[mt] = *(const bf8*)&Ab[(wm + mt * 32 + l32) * 32 + ks * 16 + lh * 8];
      #pragma unroll
      for (int nt = 0; nt < 2; ++nt)
        bfr[nt] = *(const bf8*)&Bw[(wn + nt * 32 + l32) * 32 + ks * 16 + lh * 8];
      #pragma unroll
      for (int mt = 0; mt < 2; ++mt)
        #pragma unroll
        for (int nt = 0; nt < 2; ++nt)
          acc[mt][nt] = __builtin_amdgcn_mfma_f32_32x32x16_bf16(
              af[mt], bfr[nt], acc[mt][nt], 0, 0, 0);
    }
  };

  const int nk = K >> 5;   // K multiple of 64 -> nk even
  stage(0, 0);
  for (int k = 0; k + 2 <= nk; k += 2) {
    __syncthreads();                 // drains DMA(k); buf1 readers of k-1 done
    if (k + 1 < nk) stage((k + 1) * 32, 1);
    compute(As[0], Bs[0]);
    __syncthreads();                 // drains DMA(k+1); buf0 readers done
    if (k + 2 < nk) stage((k + 2) * 32, 0);
    compute(As[1], Bs[1]);
  }

  #pragma unroll
  for (int mt = 0; mt < 2; ++mt) {
    #pragma unroll
    for (int nt = 0; nt < 2; ++nt) {
      #pragma unroll
      for (int reg = 0; reg < 16; ++reg) {
        int row = m_blk + wm + mt * 32 + 4 * lh + (reg & 3) + 8 * (reg >> 2);
        int col = n_blk + wn + nt * 32 + l32;
        float val = acc[mt][nt][reg] + bias[col];
        if (mode == 0) {
          int which = col >> 10, rr = col & 1023;
          int h = rr >> 6, d = rr & 63;
          int b = row >> 11, t = row & 2047;
          if (which == 0) val *= 0.18033688011112042f;  // 1/sqrt(D) * log2(e)
          __bf16 bv = (__bf16)val;
          size_t bh = (size_t)b * Hh + h;
          if (which == 0)      q_ws[(bh * Tt + t) * Dd + d] = bv;
          else if (which == 1) k_ws[(bh * Tt + t) * Dd + d] = bv;
          else                 v_ws[(bh * Dd + d) * Tt + t] = bv;
        } else {
          out[(size_t)row * ldo + col] = val;
        }
      }
    }
  }
}

// Flash attention with sink, fixed softmax reference m=0, log2-domain scores
// (q pre-scaled by 0.125*log2e -> exp is a bare v_exp_f32). S computed
// TRANSPOSED (A=K, B=Q); P spills as b64, reads back as b128 A-frags.
// Software pipeline: triple-buffered K/V ring; during iter kt the wave
// computes S(kt+1) (K-tile already drained at this barrier) so S-MFMA(kt+1)
// co-issues with the exp-VALU(kt) block -> MFMA/VALU overlap within a wave.
// Grid: 512 blocks; i and i+256 have qt summing to 15 (balanced pairs).
__global__ __launch_bounds__(256) void attn_kernel(
    const __bf16* __restrict__ q_ws, const __bf16* __restrict__ k_ws,
    const __bf16* __restrict__ v_ws, const float* __restrict__ sink,
    __bf16* __restrict__ y_ws)
{
  int bi = blockIdx.x;
  int qt, bhi;
  if (bi < 256) { qt = 15 - (bi >> 5); bhi = bi & 31; }
  else          { qt = (bi - 256) >> 5; bhi = (bi - 256) & 31; }
  const int h = bhi & (Hh - 1);
  const int b = bhi >> 4;
  const int tid = threadIdx.x;
  const int lane = tid & 63, wave = tid >> 6;
  const int lr = lane & 15, lq = lane >> 4;

  __shared__ __align__(16) __bf16 KsU[3][64 * 64];     // swizzled [key][d], ring
  __shared__ __align__(16) __bf16 VtU[3][64 * 64];     // swizzled [d][key], ring
  __shared__ __align__(16) __bf16 PsU[4][2 * 16 * 64]; // per-wave [qs][q][key]

  const __bf16* qp = q_ws + (size_t)bhi * Tt * Dd;
  const __bf16* kp = k_ws + (size_t)bhi * Tt * Dd;
  const __bf16* vp = v_ws + (size_t)bhi * Dd * Tt;     // [d][t]

  const int qbase = qt * 128;
  const int qlo = qbase + wave * 32;                   // wave's lowest q row

  // Q fragments: 2 subsets of 16 rows/wave, loop-invariant registers
  bf8 qf[2][2];
  #pragma unroll
  for (int qs = 0; qs < 2; ++qs) {
    const __bf16* qrow = qp + (size_t)(qlo + qs * 16 + lr) * Dd;
    qf[qs][0] = *(const bf8*)(qrow + lq * 8);
    qf[qs][1] = *(const bf8*)(qrow + 32 + lq * 8);
  }

  float rs[2] = {0.f, 0.f};   // per-lane denominator partial (q = lr, per subset)
  f4 o_acc[2][4] = {};

  const int srow_lo = wave * 8 + (lane >> 3);
  const int sslot = lane & 7;
  const int nkt = 2 * qt + 2;

  auto stage = [&](int kt2, int bsel) {
    const int kbase2 = kt2 * 64;
    #pragma unroll
    for (int ii = 0; ii < 2; ++ii) {
      const int r = ii * 32 + srow_lo;
      const int cc = sslot ^ (r & 7);            // XOR granule swizzle
      gload_lds16(kp + (size_t)(kbase2 + r) * Dd + cc * 8,
                  &KsU[bsel][ii * 2048 + wave * 512 + lane * 8]);
      gload_lds16(vp + (size_t)r * Tt + kbase2 + cc * 8,
                  &VtU[bsel][ii * 2048 + wave * 512 + lane * 8]);
    }
  };

  auto computeS = [&](const __bf16* Kb, f4 (&sA)[4][2]) {
    #pragma unroll
    for (int nt = 0; nt < 4; ++nt) {
      const int krow = nt * 16 + lr;
      const int x7 = krow & 7;
      bf8 kb0 = *(const bf8*)&Kb[krow * 64 + ((lq ^ x7) * 8)];
      bf8 kb1 = *(const bf8*)&Kb[krow * 64 + (((4 + lq) ^ x7) * 8)];
      #pragma unroll
      for (int qs = 0; qs < 2; ++qs) {
        f4 c = {};
        c = __builtin_amdgcn_mfma_f32_16x16x32_bf16(kb0, qf[qs][0], c, 0, 0, 0);
        c = __builtin_amdgcn_mfma_f32_16x16x32_bf16(kb1, qf[qs][1], c, 0, 0, 0);
        sA[nt][qs] = c;
      }
    }
  };

  f4 s_cur[4][2], s_next[4][2];

  stage(0, 0);
  __syncthreads();          // drain DMA(0)
  stage(1, 1);              // drains at first loop barrier
  computeS(KsU[0], s_cur);

  for (int kt = 0; kt < nkt; ++kt) {
    __syncthreads();        // drains DMA(kt+1); syncs ring reuse
    if (kt + 2 < nkt) stage(kt + 2, (kt + 2) % 3);

    // prefetch S for next tile — independent of exp/PV below (MFMA ∥ VALU)
    if (kt + 1 < nkt && (kt + 1) * 64 <= qlo + 31)
      computeS(KsU[(kt + 1) % 3], s_next);

    const int kbase = kt * 64;
    if (kbase <= qlo + 31) {
      __bf16* Pw = PsU[wave];
      const bool diag = (kbase + 63 > qlo);   // wave-uniform
      if (diag) {
        #pragma unroll
        for (int nt = 0; nt < 4; ++nt)
          #pragma unroll
          for (int qs = 0; qs < 2; ++qs) {
            const int qg = qlo + qs * 16 + lr;
            const int kg = kbase + nt * 16 + lq * 4;
            bf4 pb;
            #pragma unroll
            for (int r = 0; r < 4; ++r) {
              float sv = (kg + r > qg) ? -1e30f : s_cur[nt][qs][r];
              float p = ex2(sv);              // scores already in log2 domain
              rs[qs] += p;
              pb[r] = (__bf16)p;
            }
            const int G = (nt * 2 + (lq >> 1)) ^ (lr & 7);
            *(bf4*)&Pw[(qs * 16 + lr) * 64 + G * 8 + (lq & 1) * 4] = pb;
          }
      } else {
        #pragma unroll
        for (int nt = 0; nt < 4; ++nt)
          #pragma unroll
          for (int qs = 0; qs < 2; ++qs) {
            bf4 pb;
            #pragma unroll
            for (int r = 0; r < 4; ++r) {
              float p = ex2(s_cur[nt][qs][r]);
              rs[qs] += p;
              pb[r] = (__bf16)p;
            }
            const int G = (nt * 2 + (lq >> 1)) ^ (lr & 7);
            *(bf4*)&Pw[(qs * 16 + lr) * 64 + G * 8 + (lq & 1) * 4] = pb;
          }
      }
      asm volatile("s_waitcnt lgkmcnt(0)" ::: "memory");  // wave-private RAW on Pw

      const __bf16* Vb = VtU[kt % 3];
      #pragma unroll
      for (int ks = 0; ks < 2; ++ks) {
        const int pg = ((ks * 4 + lq) ^ (lr & 7)) * 8;
        bf8 pa0 = *(const bf8*)&Pw[lr * 64 + pg];
        bf8 pa1 = *(const bf8*)&Pw[(16 + lr) * 64 + pg];
        #pragma unroll
        for (int dt = 0; dt < 4; ++dt) {
          const int vrow = dt * 16 + lr;
          bf8 vb = *(const bf8*)&Vb[vrow * 64 + (((ks * 4 + lq) ^ (vrow & 7)) * 8)];
          o_acc[0][dt] = __builtin_amdgcn_mfma_f32_16x16x32_bf16(pa0, vb, o_acc[0][dt], 0, 0, 0);
          o_acc[1][dt] = __builtin_amdgcn_mfma_f32_16x16x32_bf16(pa1, vb, o_acc[1][dt], 0, 0, 0);
        }
      }
    }

    #pragma unroll
    for (int nt = 0; nt < 4; ++nt)
      #pragma unroll
      for (int qs = 0; qs < 2; ++qs)
        s_cur[nt][qs] = s_next[nt][qs];
  }

  // denominator: reduce per-lane partials over lq (lanes sharing lr)
  #pragma unroll
  for (int qs = 0; qs < 2; ++qs) {
    rs[qs] += __shfl_xor(rs[qs], 16, 64);
    rs[qs] += __shfl_xor(rs[qs], 32, 64);
  }
  const float snk = ex2(sink[h] * 1.44269504f);   // e^sink
  float inv0 = 1.0f / (rs[0] + snk);
  float inv1 = 1.0f / (rs[1] + snk);
  // redistribute: O rows are q = lq*4+r; denom lives at lane with lr == lq*4+r
  float invr[2][4];
  #pragma unroll
  for (int r = 0; r < 4; ++r) {
    invr[0][r] = __shfl(inv0, lq * 4 + r, 64);
    invr[1][r] = __shfl(inv1, lq * 4 + r, 64);
  }

  #pragma unroll
  for (int qs = 0; qs < 2; ++qs)
    #pragma unroll
    for (int dt = 0; dt < 4; ++dt)
      #pragma unroll
      for (int r = 0; r < 4; ++r) {
        int qrow = qbase + wave * 32 + qs * 16 + lq * 4 + r;
        y_ws[((size_t)b * Tt + qrow) * Cc + h * Dd + dt * 16 + lr] =
            (__bf16)(o_acc[qs][dt][r] * invr[qs][r]);
      }
}

extern "C" void kernel_launch(void* const* d_in, const int* in_sizes, int n_in,
                              void* d_out, int out_size, void* d_ws, size_t ws_size,
                              hipStream_t stream) {
  const float* x      = (const float*)d_in[0];
  const float* W_qkv  = (const float*)d_in[1];
  const float* b_qkv  = (const float*)d_in[2];
  const float* W_proj = (const float*)d_in[3];
  const float* b_proj = (const float*)d_in[4];
  const float* sinkp  = (const float*)d_in[5];
  float* out = (float*)d_out;

  const size_t n_x    = (size_t)Bb * Tt * Cc;        // 4.19M
  const size_t n_wqkv = (size_t)3 * Hh * Dd * Cc;    // 3.15M
  const size_t n_wprj = (size_t)Cc * Hh * Dd;        // 1.05M
  const size_t nqkv   = (size_t)Bb * Hh * Tt * Dd;   // 4.19M

  __bf16* xb     = (__bf16*)d_ws;          // also aliased as y_ws after QKV GEMM
  __bf16* wqkvb  = xb + n_x;
  __bf16* wprojb = wqkvb + n_wqkv;
  __bf16* q_ws   = wprojb + n_wprj;
  __bf16* k_ws   = q_ws + nqkv;
  __bf16* v_ws   = k_ws + nqkv;
  __bf16* y_ws   = xb;                     // lifetime-disjoint alias

  dim3 blk(256);
  const int cvt_blocks = (int)((n_x + n_wqkv + n_wprj) / 8 / 256);  // 4096
  cvt3_kernel<<<cvt_blocks, blk, 0, stream>>>(x, xb, (int)n_x,
                                              W_qkv, wqkvb, (int)n_wqkv,
                                              W_proj, wprojb);

  // QKV: M=4096, N=3072, K=1024
  gemm128_kernel<<<dim3(3 * Cc / 128, Bb * Tt / 128), blk, 0, stream>>>(
      xb, wqkvb, b_qkv, Cc, 0, q_ws, k_ws, v_ws, nullptr, 0);
  // attention: 512 balanced-pair blocks
  attn_kernel<<<dim3(512), blk, 0, stream>>>(q_ws, k_ws, v_ws, sinkp, y_ws);
  // proj: M=4096, N=1024, K=1024
  gemm128_kernel<<<dim3(Cc / 128, Bb * Tt / 128), blk, 0, stream>>>(
      y_ws, wprojb, b_proj, Hh * Dd, 1, nullptr, nullptr, nullptr, out, Cc);
}

// Round 12
// 186.041 us; speedup vs baseline: 1.1819x; 1.0891x over previous
//
#include <hip/hip_runtime.h>
#include <hip/hip_bf16.h>

#define Bb 2
#define Tt 2048
#define Cc 1024
#define Hh 16
#define Dd 64

typedef __bf16 bf8 __attribute__((ext_vector_type(8)));
typedef __bf16 bf4 __attribute__((ext_vector_type(4)));
typedef float f4 __attribute__((ext_vector_type(4)));

typedef __attribute__((address_space(3))) void lds_void;
typedef const __attribute__((address_space(1))) void g_void;

__device__ __forceinline__ void gload_lds16(const __bf16* g, __bf16* l) {
  __builtin_amdgcn_global_load_lds((g_void*)g, (lds_void*)l, 16, 0, 0);
}

// exp2 that lowers directly to v_exp_f32 (hw exp is base-2)
__device__ __forceinline__ float ex2(float x) { return __builtin_amdgcn_exp2f(x); }

// fused fp32 -> bf16 convert for x, W_qkv, W_proj in one launch
__global__ __launch_bounds__(256) void cvt3_kernel(
    const float* __restrict__ a, __bf16* __restrict__ oa, int na,
    const float* __restrict__ b, __bf16* __restrict__ ob, int nb,
    const float* __restrict__ c, __bf16* __restrict__ oc) {
  int gi = blockIdx.x * 256 + threadIdx.x;
  const int t0 = na >> 3, t1 = t0 + (nb >> 3);
  const float* src; __bf16* dst; int idx;
  if (gi < t0)      { src = a; dst = oa; idx = gi; }
  else if (gi < t1) { src = b; dst = ob; idx = gi - t0; }
  else              { src = c; dst = oc; idx = gi - t1; }
  const float* p = src + (size_t)idx * 8;
  float4 u = *(const float4*)p;
  float4 v = *(const float4*)(p + 4);
  bf8 r;
  r[0] = (__bf16)u.x; r[1] = (__bf16)u.y; r[2] = (__bf16)u.z; r[3] = (__bf16)u.w;
  r[4] = (__bf16)v.x; r[5] = (__bf16)v.y; r[6] = (__bf16)v.z; r[7] = (__bf16)v.w;
  *(bf8*)(dst + (size_t)idx * 8) = r;
}

// QKV GEMM: C(M,N) = A(M,K) @ W(N,K)^T + bias — ANCHOR core (128x128 tile,
// BK=32, 16x16x32 MFMA, single-buffer, contiguous global_load_lds staging;
// measured 50.6/51.1 us in fast-regime sessions).  NEW: the v third of the
// output (which==2) goes through a per-wave LDS transpose (64x72 bf16,
// 16B-aligned rows) so v_ws (B,H,D,T) is written as t-contiguous 16 B/lane
// runs instead of 2 B scatters at 4 KB stride (64 lines/inst -> ~2).
// q is pre-scaled by 0.125*log2(e); q/k written direct (32 B runs).
__global__ __launch_bounds__(256) void gemm128_kernel(
    const __bf16* __restrict__ A, const __bf16* __restrict__ W,
    const float* __restrict__ bias, int K,
    __bf16* __restrict__ q_ws, __bf16* __restrict__ k_ws,
    __bf16* __restrict__ v_ws)
{
  const int tid = threadIdx.x;
  const int lane = tid & 63, wave = tid >> 6;
  const int lr = lane & 15, lq = lane >> 4;
  const int m_blk = blockIdx.y * 128, n_blk = blockIdx.x * 128;
  const int wm = (wave & 1) * 64, wn = (wave >> 1) * 64;

  __shared__ __align__(16) __bf16 As[128 * 32];  // [row][k] contiguous (DMA layout)
  __shared__ __align__(16) __bf16 Bs[128 * 32];
  __shared__ __align__(16) __bf16 Epi[4][64 * 72];  // per-wave v-transpose buffer

  const int srow = tid >> 2, scol = (tid & 3) * 8;
  const __bf16* ag0 = A + (size_t)(m_blk + srow) * K + scol;
  const __bf16* ag1 = A + (size_t)(m_blk + 64 + srow) * K + scol;
  const __bf16* bg0 = W + (size_t)(n_blk + srow) * K + scol;
  const __bf16* bg1 = W + (size_t)(n_blk + 64 + srow) * K + scol;
  __bf16* al0 = As + tid * 8;          // byte off = tid*16 (wave-uniform base + lane*16)
  __bf16* al1 = As + 2048 + tid * 8;
  __bf16* bl0 = Bs + tid * 8;
  __bf16* bl1 = Bs + 2048 + tid * 8;

  f4 acc[4][4] = {};
  for (int k0 = 0; k0 < K; k0 += 32) {
    gload_lds16(ag0 + k0, al0);
    gload_lds16(ag1 + k0, al1);
    gload_lds16(bg0 + k0, bl0);
    gload_lds16(bg1 + k0, bl1);
    __syncthreads();   // drains vmcnt (global_load_lds) before reads

    bf8 af[4], bfr[4];
    #pragma unroll
    for (int i = 0; i < 4; ++i)
      af[i] = *(const bf8*)&As[(wm + i * 16 + lr) * 32 + lq * 8];
    #pragma unroll
    for (int j = 0; j < 4; ++j)
      bfr[j] = *(const bf8*)&Bs[(wn + j * 16 + lr) * 32 + lq * 8];
    #pragma unroll
    for (int i = 0; i < 4; ++i)
      #pragma unroll
      for (int j = 0; j < 4; ++j)
        acc[i][j] = __builtin_amdgcn_mfma_f32_16x16x32_bf16(af[i], bfr[j], acc[i][j], 0, 0, 0);
    __syncthreads();   // LDS reads done before next-iter staging overwrites
  }

  const int col0 = n_blk + wn;          // 64-aligned -> which/h wave-uniform
  const int which = col0 >> 10;
  const int b = m_blk >> 11;            // 128-row blocks never straddle b
  const int h = (col0 & 1023) >> 6;
  const size_t bh = (size_t)b * Hh + h;

  if (which == 2) {
    // v: transpose through per-wave LDS, write t-contiguous
    __bf16* E = Epi[wave];
    #pragma unroll
    for (int j = 0; j < 4; ++j) {
      float bv = bias[col0 + j * 16 + lr];
      #pragma unroll
      for (int i = 0; i < 4; ++i)
        #pragma unroll
        for (int r = 0; r < 4; ++r)
          E[(j * 16 + lr) * 72 + i * 16 + lq * 4 + r] = (__bf16)(acc[i][j][r] + bv);
    }
    asm volatile("s_waitcnt lgkmcnt(0)" ::: "memory");  // wave-private RAW
    const int t0 = (m_blk + wm) & 2047;
    const int dd = lane >> 3, tl = (lane & 7) * 8;
    #pragma unroll
    for (int di = 0; di < 8; ++di) {
      int d = di * 8 + dd;
      bf8 vv = *(const bf8*)&E[d * 72 + tl];
      *(bf8*)&v_ws[(bh * Dd + d) * Tt + t0 + tl] = vv;
    }
  } else {
    __bf16* dst = (which == 0) ? q_ws : k_ws;
    const float scl = (which == 0) ? 0.18033688011112042f : 1.0f;  // 1/sqrt(D)*log2e
    #pragma unroll
    for (int i = 0; i < 4; ++i) {
      #pragma unroll
      for (int j = 0; j < 4; ++j) {
        #pragma unroll
        for (int r = 0; r < 4; ++r) {
          int row = m_blk + wm + i * 16 + lq * 4 + r;  // C/D: row = 4*quad + reg
          int col = col0 + j * 16 + lr;                // C/D: col = lane&15
          float val = (acc[i][j][r] + bias[col]) * scl;
          int d = col & 63, t = row & 2047;
          dst[(bh * Tt + t) * Dd + d] = (__bf16)val;
        }
      }
    }
  }
}

// Proj GEMM: out(M,Cc) = A(M,K) @ W(Cc,K)^T + bias, fp32 out.  64x64 tiles ->
// 1024 blocks (4/CU): in this latency-bound regime hiding comes from TLP
// (R7-R10 lesson), and the old 128x128/256-block version (1 block/CU) ran
// ~50 us for 8.6 GF.  8 KB LDS, single-buffer, anchor staging/fragments.
__global__ __launch_bounds__(256) void gemm64_kernel(
    const __bf16* __restrict__ A, const __bf16* __restrict__ W,
    const float* __restrict__ bias, int K, float* __restrict__ out, int ldo)
{
  const int tid = threadIdx.x;
  const int lane = tid & 63, wave = tid >> 6;
  const int lr = lane & 15, lq = lane >> 4;
  const int m_blk = blockIdx.y * 64, n_blk = blockIdx.x * 64;
  const int wm = (wave & 1) * 32, wn = (wave >> 1) * 32;

  __shared__ __align__(16) __bf16 As[64 * 32];
  __shared__ __align__(16) __bf16 Bs[64 * 32];

  const int srow = tid >> 2, scol = (tid & 3) * 8;
  const __bf16* ag = A + (size_t)(m_blk + srow) * K + scol;
  const __bf16* bg = W + (size_t)(n_blk + srow) * K + scol;
  __bf16* al = As + tid * 8;
  __bf16* bl = Bs + tid * 8;

  f4 acc[2][2] = {};
  for (int k0 = 0; k0 < K; k0 += 32) {
    gload_lds16(ag + k0, al);
    gload_lds16(bg + k0, bl);
    __syncthreads();

    bf8 af[2], bfr[2];
    #pragma unroll
    for (int i = 0; i < 2; ++i)
      af[i] = *(const bf8*)&As[(wm + i * 16 + lr) * 32 + lq * 8];
    #pragma unroll
    for (int j = 0; j < 2; ++j)
      bfr[j] = *(const bf8*)&Bs[(wn + j * 16 + lr) * 32 + lq * 8];
    #pragma unroll
    for (int i = 0; i < 2; ++i)
      #pragma unroll
      for (int j = 0; j < 2; ++j)
        acc[i][j] = __builtin_amdgcn_mfma_f32_16x16x32_bf16(af[i], bfr[j], acc[i][j], 0, 0, 0);
    __syncthreads();
  }

  #pragma unroll
  for (int i = 0; i < 2; ++i)
    #pragma unroll
    for (int j = 0; j < 2; ++j)
      #pragma unroll
      for (int r = 0; r < 4; ++r) {
        int row = m_blk + wm + i * 16 + lq * 4 + r;
        int col = n_blk + wn + j * 16 + lr;
        out[(size_t)row * ldo + col] = acc[i][j][r] + bias[col];
      }
}

// Flash attention with sink, fixed softmax reference m=0, log2-domain scores
// (q pre-scaled by 0.125*log2e -> exp is a bare v_exp_f32). S computed
// TRANSPOSED (A=K, B=Q); P spills as b64, reads back as b128 A-frags.
// Software pipeline: triple-buffered K/V ring; during iter kt the wave
// computes S(kt+1) (K-tile already drained at this barrier) so S-MFMA(kt+1)
// co-issues with the exp-VALU(kt) block -> MFMA/VALU overlap within a wave.
// Grid: 512 blocks; i and i+256 have qt summing to 15 (balanced pairs).
__global__ __launch_bounds__(256) void attn_kernel(
    const __bf16* __restrict__ q_ws, const __bf16* __restrict__ k_ws,
    const __bf16* __restrict__ v_ws, const float* __restrict__ sink,
    __bf16* __restrict__ y_ws)
{
  int bi = blockIdx.x;
  int qt, bhi;
  if (bi < 256) { qt = 15 - (bi >> 5); bhi = bi & 31; }
  else          { qt = (bi - 256) >> 5; bhi = (bi - 256) & 31; }
  const int h = bhi & (Hh - 1);
  const int b = bhi >> 4;
  const int tid = threadIdx.x;
  const int lane = tid & 63, wave = tid >> 6;
  const int lr = lane & 15, lq = lane >> 4;

  __shared__ __align__(16) __bf16 KsU[3][64 * 64];     // swizzled [key][d], ring
  __shared__ __align__(16) __bf16 VtU[3][64 * 64];     // swizzled [d][key], ring
  __shared__ __align__(16) __bf16 PsU[4][2 * 16 * 64]; // per-wave [qs][q][key]

  const __bf16* qp = q_ws + (size_t)bhi * Tt * Dd;
  const __bf16* kp = k_ws + (size_t)bhi * Tt * Dd;
  const __bf16* vp = v_ws + (size_t)bhi * Dd * Tt;     // [d][t]

  const int qbase = qt * 128;
  const int qlo = qbase + wave * 32;                   // wave's lowest q row

  // Q fragments: 2 subsets of 16 rows/wave, loop-invariant registers
  bf8 qf[2][2];
  #pragma unroll
  for (int qs = 0; qs < 2; ++qs) {
    const __bf16* qrow = qp + (size_t)(qlo + qs * 16 + lr) * Dd;
    qf[qs][0] = *(const bf8*)(qrow + lq * 8);
    qf[qs][1] = *(const bf8*)(qrow + 32 + lq * 8);
  }

  float rs[2] = {0.f, 0.f};   // per-lane denominator partial (q = lr, per subset)
  f4 o_acc[2][4] = {};

  const int srow_lo = wave * 8 + (lane >> 3);
  const int sslot = lane & 7;
  const int nkt = 2 * qt + 2;

  auto stage = [&](int kt2, int bsel) {
    const int kbase2 = kt2 * 64;
    #pragma unroll
    for (int ii = 0; ii < 2; ++ii) {
      const int r = ii * 32 + srow_lo;
      const int cc = sslot ^ (r & 7);            // XOR granule swizzle
      gload_lds16(kp + (size_t)(kbase2 + r) * Dd + cc * 8,
                  &KsU[bsel][ii * 2048 + wave * 512 + lane * 8]);
      gload_lds16(vp + (size_t)r * Tt + kbase2 + cc * 8,
                  &VtU[bsel][ii * 2048 + wave * 512 + lane * 8]);
    }
  };

  auto computeS = [&](const __bf16* Kb, f4 (&sA)[4][2]) {
    #pragma unroll
    for (int nt = 0; nt < 4; ++nt) {
      const int krow = nt * 16 + lr;
      const int x7 = krow & 7;
      bf8 kb0 = *(const bf8*)&Kb[krow * 64 + ((lq ^ x7) * 8)];
      bf8 kb1 = *(const bf8*)&Kb[krow * 64 + (((4 + lq) ^ x7) * 8)];
      #pragma unroll
      for (int qs = 0; qs < 2; ++qs) {
        f4 c = {};
        c = __builtin_amdgcn_mfma_f32_16x16x32_bf16(kb0, qf[qs][0], c, 0, 0, 0);
        c = __builtin_amdgcn_mfma_f32_16x16x32_bf16(kb1, qf[qs][1], c, 0, 0, 0);
        sA[nt][qs] = c;
      }
    }
  };

  f4 s_cur[4][2], s_next[4][2];

  stage(0, 0);
  __syncthreads();          // drain DMA(0)
  stage(1, 1);              // drains at first loop barrier
  computeS(KsU[0], s_cur);

  for (int kt = 0; kt < nkt; ++kt) {
    __syncthreads();        // drains DMA(kt+1); syncs ring reuse
    if (kt + 2 < nkt) stage(kt + 2, (kt + 2) % 3);

    // prefetch S for next tile — independent of exp/PV below (MFMA ∥ VALU)
    if (kt + 1 < nkt && (kt + 1) * 64 <= qlo + 31)
      computeS(KsU[(kt + 1) % 3], s_next);

    const int kbase = kt * 64;
    if (kbase <= qlo + 31) {
      __bf16* Pw = PsU[wave];
      const bool diag = (kbase + 63 > qlo);   // wave-uniform
      if (diag) {
        #pragma unroll
        for (int nt = 0; nt < 4; ++nt)
          #pragma unroll
          for (int qs = 0; qs < 2; ++qs) {
            const int qg = qlo + qs * 16 + lr;
            const int kg = kbase + nt * 16 + lq * 4;
            bf4 pb;
            #pragma unroll
            for (int r = 0; r < 4; ++r) {
              float sv = (kg + r > qg) ? -1e30f : s_cur[nt][qs][r];
              float p = ex2(sv);              // scores already in log2 domain
              rs[qs] += p;
              pb[r] = (__bf16)p;
            }
            const int G = (nt * 2 + (lq >> 1)) ^ (lr & 7);
            *(bf4*)&Pw[(qs * 16 + lr) * 64 + G * 8 + (lq & 1) * 4] = pb;
          }
      } else {
        #pragma unroll
        for (int nt = 0; nt < 4; ++nt)
          #pragma unroll
          for (int qs = 0; qs < 2; ++qs) {
            bf4 pb;
            #pragma unroll
            for (int r = 0; r < 4; ++r) {
              float p = ex2(s_cur[nt][qs][r]);
              rs[qs] += p;
              pb[r] = (__bf16)p;
            }
            const int G = (nt * 2 + (lq >> 1)) ^ (lr & 7);
            *(bf4*)&Pw[(qs * 16 + lr) * 64 + G * 8 + (lq & 1) * 4] = pb;
          }
      }
      asm volatile("s_waitcnt lgkmcnt(0)" ::: "memory");  // wave-private RAW on Pw

      const __bf16* Vb = VtU[kt % 3];
      #pragma unroll
      for (int ks = 0; ks < 2; ++ks) {
        const int pg = ((ks * 4 + lq) ^ (lr & 7)) * 8;
        bf8 pa0 = *(const bf8*)&Pw[lr * 64 + pg];
        bf8 pa1 = *(const bf8*)&Pw[(16 + lr) * 64 + pg];
        #pragma unroll
        for (int dt = 0; dt < 4; ++dt) {
          const int vrow = dt * 16 + lr;
          bf8 vb = *(const bf8*)&Vb[vrow * 64 + (((ks * 4 + lq) ^ (vrow & 7)) * 8)];
          o_acc[0][dt] = __builtin_amdgcn_mfma_f32_16x16x32_bf16(pa0, vb, o_acc[0][dt], 0, 0, 0);
          o_acc[1][dt] = __builtin_amdgcn_mfma_f32_16x16x32_bf16(pa1, vb, o_acc[1][dt], 0, 0, 0);
        }
      }
    }

    #pragma unroll
    for (int nt = 0; nt < 4; ++nt)
      #pragma unroll
      for (int qs = 0; qs < 2; ++qs)
        s_cur[nt][qs] = s_next[nt][qs];
  }

  // denominator: reduce per-lane partials over lq (lanes sharing lr)
  #pragma unroll
  for (int qs = 0; qs < 2; ++qs) {
    rs[qs] += __shfl_xor(rs[qs], 16, 64);
    rs[qs] += __shfl_xor(rs[qs], 32, 64);
  }
  const float snk = ex2(sink[h] * 1.44269504f);   // e^sink
  float inv0 = 1.0f / (rs[0] + snk);
  float inv1 = 1.0f / (rs[1] + snk);
  // redistribute: O rows are q = lq*4+r; denom lives at lane with lr == lq*4+r
  float invr[2][4];
  #pragma unroll
  for (int r = 0; r < 4; ++r) {
    invr[0][r] = __shfl(inv0, lq * 4 + r, 64);
    invr[1][r] = __shfl(inv1, lq * 4 + r, 64);
  }

  #pragma unroll
  for (int qs = 0; qs < 2; ++qs)
    #pragma unroll
    for (int dt = 0; dt < 4; ++dt)
      #pragma unroll
      for (int r = 0; r < 4; ++r) {
        int qrow = qbase + wave * 32 + qs * 16 + lq * 4 + r;
        y_ws[((size_t)b * Tt + qrow) * Cc + h * Dd + dt * 16 + lr] =
            (__bf16)(o_acc[qs][dt][r] * invr[qs][r]);
      }
}

extern "C" void kernel_launch(void* const* d_in, const int* in_sizes, int n_in,
                              void* d_out, int out_size, void* d_ws, size_t ws_size,
                              hipStream_t stream) {
  const float* x      = (const float*)d_in[0];
  const float* W_qkv  = (const float*)d_in[1];
  const float* b_qkv  = (const float*)d_in[2];
  const float* W_proj = (const float*)d_in[3];
  const float* b_proj = (const float*)d_in[4];
  const float* sinkp  = (const float*)d_in[5];
  float* out = (float*)d_out;

  const size_t n_x    = (size_t)Bb * Tt * Cc;        // 4.19M
  const size_t n_wqkv = (size_t)3 * Hh * Dd * Cc;    // 3.15M
  const size_t n_wprj = (size_t)Cc * Hh * Dd;        // 1.05M
  const size_t nqkv   = (size_t)Bb * Hh * Tt * Dd;   // 4.19M

  __bf16* xb     = (__bf16*)d_ws;          // also aliased as y_ws after QKV GEMM
  __bf16* wqkvb  = xb + n_x;
  __bf16* wprojb = wqkvb + n_wqkv;
  __bf16* q_ws   = wprojb + n_wprj;
  __bf16* k_ws   = q_ws + nqkv;
  __bf16* v_ws   = k_ws + nqkv;
  __bf16* y_ws   = xb;                     // lifetime-disjoint alias

  dim3 blk(256);
  const int cvt_blocks = (int)((n_x + n_wqkv + n_wprj) / 8 / 256);  // 4096
  cvt3_kernel<<<cvt_blocks, blk, 0, stream>>>(x, xb, (int)n_x,
                                              W_qkv, wqkvb, (int)n_wqkv,
                                              W_proj, wprojb);

  // QKV: M=4096, N=3072, K=1024 — 768 blocks (3/CU)
  gemm128_kernel<<<dim3(3 * Cc / 128, Bb * Tt / 128), blk, 0, stream>>>(
      xb, wqkvb, b_qkv, Cc, q_ws, k_ws, v_ws);
  // attention: 512 balanced-pair blocks
  attn_kernel<<<dim3(512), blk, 0, stream>>>(q_ws, k_ws, v_ws, sinkp, y_ws);
  // proj: M=4096, N=1024, K=1024 — 64x64 tiles -> 1024 blocks (4/CU)
  gemm64_kernel<<<dim3(Cc / 64, Bb * Tt / 64), blk, 0, stream>>>(
      y_ws, wprojb, b_proj, Hh * Dd, out, Cc);
}

// Round 13
// 180.322 us; speedup vs baseline: 1.2194x; 1.0317x over previous
//
#include <hip/hip_runtime.h>
#include <hip/hip_bf16.h>

#define Bb 2
#define Tt 2048
#define Cc 1024
#define Hh 16
#define Dd 64

typedef __bf16 bf8 __attribute__((ext_vector_type(8)));
typedef __bf16 bf4 __attribute__((ext_vector_type(4)));
typedef float f4 __attribute__((ext_vector_type(4)));

typedef __attribute__((address_space(3))) void lds_void;
typedef const __attribute__((address_space(1))) void g_void;

__device__ __forceinline__ void gload_lds16(const __bf16* g, __bf16* l) {
  __builtin_amdgcn_global_load_lds((g_void*)g, (lds_void*)l, 16, 0, 0);
}

// exp2 that lowers directly to v_exp_f32 (hw exp is base-2)
__device__ __forceinline__ float ex2(float x) { return __builtin_amdgcn_exp2f(x); }

// fused fp32 -> bf16 convert for x, W_qkv, W_proj in one launch
__global__ __launch_bounds__(256) void cvt3_kernel(
    const float* __restrict__ a, __bf16* __restrict__ oa, int na,
    const float* __restrict__ b, __bf16* __restrict__ ob, int nb,
    const float* __restrict__ c, __bf16* __restrict__ oc) {
  int gi = blockIdx.x * 256 + threadIdx.x;
  const int t0 = na >> 3, t1 = t0 + (nb >> 3);
  const float* src; __bf16* dst; int idx;
  if (gi < t0)      { src = a; dst = oa; idx = gi; }
  else if (gi < t1) { src = b; dst = ob; idx = gi - t0; }
  else              { src = c; dst = oc; idx = gi - t1; }
  const float* p = src + (size_t)idx * 8;
  float4 u = *(const float4*)p;
  float4 v = *(const float4*)(p + 4);
  bf8 r;
  r[0] = (__bf16)u.x; r[1] = (__bf16)u.y; r[2] = (__bf16)u.z; r[3] = (__bf16)u.w;
  r[4] = (__bf16)v.x; r[5] = (__bf16)v.y; r[6] = (__bf16)v.z; r[7] = (__bf16)v.w;
  *(bf8*)(dst + (size_t)idx * 8) = r;
}

// QKV GEMM: ANCHOR core (128x128, BK=32, 16x16x32, single-buffer, contiguous
// DMA staging).  v third goes through a per-wave LDS transpose so v_ws
// (B,H,D,T) is written t-contiguous (16 B runs).  q pre-scaled 0.125*log2e.
__global__ __launch_bounds__(256) void gemm128_kernel(
    const __bf16* __restrict__ A, const __bf16* __restrict__ W,
    const float* __restrict__ bias, int K,
    __bf16* __restrict__ q_ws, __bf16* __restrict__ k_ws,
    __bf16* __restrict__ v_ws)
{
  const int tid = threadIdx.x;
  const int lane = tid & 63, wave = tid >> 6;
  const int lr = lane & 15, lq = lane >> 4;
  const int m_blk = blockIdx.y * 128, n_blk = blockIdx.x * 128;
  const int wm = (wave & 1) * 64, wn = (wave >> 1) * 64;

  __shared__ __align__(16) __bf16 As[128 * 32];  // [row][k] contiguous (DMA layout)
  __shared__ __align__(16) __bf16 Bs[128 * 32];
  __shared__ __align__(16) __bf16 Epi[4][64 * 72];  // per-wave v-transpose buffer

  const int srow = tid >> 2, scol = (tid & 3) * 8;
  const __bf16* ag0 = A + (size_t)(m_blk + srow) * K + scol;
  const __bf16* ag1 = A + (size_t)(m_blk + 64 + srow) * K + scol;
  const __bf16* bg0 = W + (size_t)(n_blk + srow) * K + scol;
  const __bf16* bg1 = W + (size_t)(n_blk + 64 + srow) * K + scol;
  __bf16* al0 = As + tid * 8;          // byte off = tid*16 (wave-uniform base + lane*16)
  __bf16* al1 = As + 2048 + tid * 8;
  __bf16* bl0 = Bs + tid * 8;
  __bf16* bl1 = Bs + 2048 + tid * 8;

  f4 acc[4][4] = {};
  for (int k0 = 0; k0 < K; k0 += 32) {
    gload_lds16(ag0 + k0, al0);
    gload_lds16(ag1 + k0, al1);
    gload_lds16(bg0 + k0, bl0);
    gload_lds16(bg1 + k0, bl1);
    __syncthreads();   // drains vmcnt (global_load_lds) before reads

    bf8 af[4], bfr[4];
    #pragma unroll
    for (int i = 0; i < 4; ++i)
      af[i] = *(const bf8*)&As[(wm + i * 16 + lr) * 32 + lq * 8];
    #pragma unroll
    for (int j = 0; j < 4; ++j)
      bfr[j] = *(const bf8*)&Bs[(wn + j * 16 + lr) * 32 + lq * 8];
    #pragma unroll
    for (int i = 0; i < 4; ++i)
      #pragma unroll
      for (int j = 0; j < 4; ++j)
        acc[i][j] = __builtin_amdgcn_mfma_f32_16x16x32_bf16(af[i], bfr[j], acc[i][j], 0, 0, 0);
    __syncthreads();   // LDS reads done before next-iter staging overwrites
  }

  const int col0 = n_blk + wn;          // 64-aligned -> which/h wave-uniform
  const int which = col0 >> 10;
  const int b = m_blk >> 11;            // 128-row blocks never straddle b
  const int h = (col0 & 1023) >> 6;
  const size_t bh = (size_t)b * Hh + h;

  if (which == 2) {
    // v: transpose through per-wave LDS, write t-contiguous
    __bf16* E = Epi[wave];
    #pragma unroll
    for (int j = 0; j < 4; ++j) {
      float bv = bias[col0 + j * 16 + lr];
      #pragma unroll
      for (int i = 0; i < 4; ++i)
        #pragma unroll
        for (int r = 0; r < 4; ++r)
          E[(j * 16 + lr) * 72 + i * 16 + lq * 4 + r] = (__bf16)(acc[i][j][r] + bv);
    }
    asm volatile("s_waitcnt lgkmcnt(0)" ::: "memory");  // wave-private RAW
    const int t0 = (m_blk + wm) & 2047;
    const int dd = lane >> 3, tl = (lane & 7) * 8;
    #pragma unroll
    for (int di = 0; di < 8; ++di) {
      int d = di * 8 + dd;
      bf8 vv = *(const bf8*)&E[d * 72 + tl];
      *(bf8*)&v_ws[(bh * Dd + d) * Tt + t0 + tl] = vv;
    }
  } else {
    __bf16* dst = (which == 0) ? q_ws : k_ws;
    const float scl = (which == 0) ? 0.18033688011112042f : 1.0f;  // 1/sqrt(D)*log2e
    #pragma unroll
    for (int i = 0; i < 4; ++i) {
      #pragma unroll
      for (int j = 0; j < 4; ++j) {
        #pragma unroll
        for (int r = 0; r < 4; ++r) {
          int row = m_blk + wm + i * 16 + lq * 4 + r;  // C/D: row = 4*quad + reg
          int col = col0 + j * 16 + lr;                // C/D: col = lane&15
          float val = (acc[i][j][r] + bias[col]) * scl;
          int d = col & 63, t = row & 2047;
          dst[(bh * Tt + t) * Dd + d] = (__bf16)val;
        }
      }
    }
  }
}

// Proj GEMM: 64x64 tiles -> 1024 blocks (4/CU TLP).  8 KB LDS, single-buffer.
__global__ __launch_bounds__(256) void gemm64_kernel(
    const __bf16* __restrict__ A, const __bf16* __restrict__ W,
    const float* __restrict__ bias, int K, float* __restrict__ out, int ldo)
{
  const int tid = threadIdx.x;
  const int lane = tid & 63, wave = tid >> 6;
  const int lr = lane & 15, lq = lane >> 4;
  const int m_blk = blockIdx.y * 64, n_blk = blockIdx.x * 64;
  const int wm = (wave & 1) * 32, wn = (wave >> 1) * 32;

  __shared__ __align__(16) __bf16 As[64 * 32];
  __shared__ __align__(16) __bf16 Bs[64 * 32];

  const int srow = tid >> 2, scol = (tid & 3) * 8;
  const __bf16* ag = A + (size_t)(m_blk + srow) * K + scol;
  const __bf16* bg = W + (size_t)(n_blk + srow) * K + scol;
  __bf16* al = As + tid * 8;
  __bf16* bl = Bs + tid * 8;

  f4 acc[2][2] = {};
  for (int k0 = 0; k0 < K; k0 += 32) {
    gload_lds16(ag + k0, al);
    gload_lds16(bg + k0, bl);
    __syncthreads();

    bf8 af[2], bfr[2];
    #pragma unroll
    for (int i = 0; i < 2; ++i)
      af[i] = *(const bf8*)&As[(wm + i * 16 + lr) * 32 + lq * 8];
    #pragma unroll
    for (int j = 0; j < 2; ++j)
      bfr[j] = *(const bf8*)&Bs[(wn + j * 16 + lr) * 32 + lq * 8];
    #pragma unroll
    for (int i = 0; i < 2; ++i)
      #pragma unroll
      for (int j = 0; j < 2; ++j)
        acc[i][j] = __builtin_amdgcn_mfma_f32_16x16x32_bf16(af[i], bfr[j], acc[i][j], 0, 0, 0);
    __syncthreads();
  }

  #pragma unroll
  for (int i = 0; i < 2; ++i)
    #pragma unroll
    for (int j = 0; j < 2; ++j)
      #pragma unroll
      for (int r = 0; r < 4; ++r) {
        int row = m_blk + wm + i * 16 + lq * 4 + r;
        int col = n_blk + wn + j * 16 + lr;
        out[(size_t)row * ldo + col] = acc[i][j][r] + bias[col];
      }
}

// Flash attention with sink, fixed softmax reference m=0, log2-domain scores.
// R13: 512-thread blocks (8 waves x 16 q-rows) — same 128 q/block and grid
// (512), but 16 waves/CU = 4/SIMD (2x TLP vs R12's 12.7% occupancy).  LDS
// traffic/MFMA doubles per wave, affordable: pipe floor ~13 us vs 51 us wall.
// Triple-ring K/V DMA + S(kt+1) prefetch pipeline retained.
__global__ __launch_bounds__(512) void attn_kernel(
    const __bf16* __restrict__ q_ws, const __bf16* __restrict__ k_ws,
    const __bf16* __restrict__ v_ws, const float* __restrict__ sink,
    __bf16* __restrict__ y_ws)
{
  int bi = blockIdx.x;
  int qt, bhi;
  if (bi < 256) { qt = 15 - (bi >> 5); bhi = bi & 31; }
  else          { qt = (bi - 256) >> 5; bhi = (bi - 256) & 31; }
  const int h = bhi & (Hh - 1);
  const int b = bhi >> 4;
  const int tid = threadIdx.x;
  const int lane = tid & 63, wave = tid >> 6;          // wave 0..7
  const int lr = lane & 15, lq = lane >> 4;

  __shared__ __align__(16) __bf16 KsU[3][64 * 64];     // swizzled [key][d], ring
  __shared__ __align__(16) __bf16 VtU[3][64 * 64];     // swizzled [d][key], ring
  __shared__ __align__(16) __bf16 PsU[8][16 * 64];     // per-wave [q][key]

  const __bf16* qp = q_ws + (size_t)bhi * Tt * Dd;
  const __bf16* kp = k_ws + (size_t)bhi * Tt * Dd;
  const __bf16* vp = v_ws + (size_t)bhi * Dd * Tt;     // [d][t]

  const int qbase = qt * 128;
  const int qlo = qbase + wave * 16;                   // wave's lowest q row

  // Q fragments: 16 rows/wave, loop-invariant registers
  bf8 qf[2];
  {
    const __bf16* qrow = qp + (size_t)(qlo + lr) * Dd;
    qf[0] = *(const bf8*)(qrow + lq * 8);
    qf[1] = *(const bf8*)(qrow + 32 + lq * 8);
  }

  float rs = 0.f;             // per-lane denominator partial (q = lr)
  f4 o_acc[4] = {};

  // staging: 512 threads cover 64 rows x 8 slots, one K chunk + one V chunk each
  const int srow_g = tid >> 3;          // 0..63
  const int sslot = tid & 7;
  const int nkt = 2 * qt + 2;

  auto stage = [&](int kt2, int bsel) {
    const int kbase2 = kt2 * 64;
    const int cc = sslot ^ (srow_g & 7);           // XOR granule swizzle
    gload_lds16(kp + (size_t)(kbase2 + srow_g) * Dd + cc * 8,
                &KsU[bsel][wave * 512 + lane * 8]);
    gload_lds16(vp + (size_t)srow_g * Tt + kbase2 + cc * 8,
                &VtU[bsel][wave * 512 + lane * 8]);
  };

  auto computeS = [&](const __bf16* Kb, f4 (&sA)[4]) {
    #pragma unroll
    for (int nt = 0; nt < 4; ++nt) {
      const int krow = nt * 16 + lr;
      const int x7 = krow & 7;
      bf8 kb0 = *(const bf8*)&Kb[krow * 64 + ((lq ^ x7) * 8)];
      bf8 kb1 = *(const bf8*)&Kb[krow * 64 + (((4 + lq) ^ x7) * 8)];
      f4 c = {};
      c = __builtin_amdgcn_mfma_f32_16x16x32_bf16(kb0, qf[0], c, 0, 0, 0);
      c = __builtin_amdgcn_mfma_f32_16x16x32_bf16(kb1, qf[1], c, 0, 0, 0);
      sA[nt] = c;
    }
  };

  f4 s_cur[4], s_next[4];

  stage(0, 0);
  __syncthreads();          // drain DMA(0)
  stage(1, 1);              // drains at first loop barrier
  computeS(KsU[0], s_cur);

  for (int kt = 0; kt < nkt; ++kt) {
    __syncthreads();        // drains DMA(kt+1); syncs ring reuse
    if (kt + 2 < nkt) stage(kt + 2, (kt + 2) % 3);

    // prefetch S for next tile — independent of exp/PV below (MFMA ∥ VALU)
    if (kt + 1 < nkt && (kt + 1) * 64 <= qlo + 15)
      computeS(KsU[(kt + 1) % 3], s_next);

    const int kbase = kt * 64;
    if (kbase <= qlo + 15) {
      __bf16* Pw = PsU[wave];
      const bool diag = (kbase + 63 > qlo);   // wave-uniform
      if (diag) {
        #pragma unroll
        for (int nt = 0; nt < 4; ++nt) {
          const int qg = qlo + lr;
          const int kg = kbase + nt * 16 + lq * 4;
          bf4 pb;
          #pragma unroll
          for (int r = 0; r < 4; ++r) {
            float sv = (kg + r > qg) ? -1e30f : s_cur[nt][r];
            float p = ex2(sv);              // scores already in log2 domain
            rs += p;
            pb[r] = (__bf16)p;
          }
          const int G = (nt * 2 + (lq >> 1)) ^ (lr & 7);
          *(bf4*)&Pw[lr * 64 + G * 8 + (lq & 1) * 4] = pb;
        }
      } else {
        #pragma unroll
        for (int nt = 0; nt < 4; ++nt) {
          bf4 pb;
          #pragma unroll
          for (int r = 0; r < 4; ++r) {
            float p = ex2(s_cur[nt][r]);
            rs += p;
            pb[r] = (__bf16)p;
          }
          const int G = (nt * 2 + (lq >> 1)) ^ (lr & 7);
          *(bf4*)&Pw[lr * 64 + G * 8 + (lq & 1) * 4] = pb;
        }
      }
      asm volatile("s_waitcnt lgkmcnt(0)" ::: "memory");  // wave-private RAW on Pw

      const __bf16* Vb = VtU[kt % 3];
      #pragma unroll
      for (int ks = 0; ks < 2; ++ks) {
        const int pg = ((ks * 4 + lq) ^ (lr & 7)) * 8;
        bf8 pa = *(const bf8*)&Pw[lr * 64 + pg];
        #pragma unroll
        for (int dt = 0; dt < 4; ++dt) {
          const int vrow = dt * 16 + lr;
          bf8 vb = *(const bf8*)&Vb[vrow * 64 + (((ks * 4 + lq) ^ (vrow & 7)) * 8)];
          o_acc[dt] = __builtin_amdgcn_mfma_f32_16x16x32_bf16(pa, vb, o_acc[dt], 0, 0, 0);
        }
      }
    }

    #pragma unroll
    for (int nt = 0; nt < 4; ++nt)
      s_cur[nt] = s_next[nt];
  }

  // denominator: reduce per-lane partials over lq (lanes sharing lr)
  rs += __shfl_xor(rs, 16, 64);
  rs += __shfl_xor(rs, 32, 64);
  const float snk = ex2(sink[h] * 1.44269504f);   // e^sink
  float inv = 1.0f / (rs + snk);
  // redistribute: O rows are q = lq*4+r; denom lives at lane with lr == lq*4+r
  float invr[4];
  #pragma unroll
  for (int r = 0; r < 4; ++r)
    invr[r] = __shfl(inv, lq * 4 + r, 64);

  #pragma unroll
  for (int dt = 0; dt < 4; ++dt)
    #pragma unroll
    for (int r = 0; r < 4; ++r) {
      int qrow = qlo + lq * 4 + r;
      y_ws[((size_t)b * Tt + qrow) * Cc + h * Dd + dt * 16 + lr] =
          (__bf16)(o_acc[dt][r] * invr[r]);
    }
}

extern "C" void kernel_launch(void* const* d_in, const int* in_sizes, int n_in,
                              void* d_out, int out_size, void* d_ws, size_t ws_size,
                              hipStream_t stream) {
  const float* x      = (const float*)d_in[0];
  const float* W_qkv  = (const float*)d_in[1];
  const float* b_qkv  = (const float*)d_in[2];
  const float* W_proj = (const float*)d_in[3];
  const float* b_proj = (const float*)d_in[4];
  const float* sinkp  = (const float*)d_in[5];
  float* out = (float*)d_out;

  const size_t n_x    = (size_t)Bb * Tt * Cc;        // 4.19M
  const size_t n_wqkv = (size_t)3 * Hh * Dd * Cc;    // 3.15M
  const size_t n_wprj = (size_t)Cc * Hh * Dd;        // 1.05M
  const size_t nqkv   = (size_t)Bb * Hh * Tt * Dd;   // 4.19M

  __bf16* xb     = (__bf16*)d_ws;          // also aliased as y_ws after QKV GEMM
  __bf16* wqkvb  = xb + n_x;
  __bf16* wprojb = wqkvb + n_wqkv;
  __bf16* q_ws   = wprojb + n_wprj;
  __bf16* k_ws   = q_ws + nqkv;
  __bf16* v_ws   = k_ws + nqkv;
  __bf16* y_ws   = xb;                     // lifetime-disjoint alias

  dim3 blk(256);
  const int cvt_blocks = (int)((n_x + n_wqkv + n_wprj) / 8 / 256);  // 4096
  cvt3_kernel<<<cvt_blocks, blk, 0, stream>>>(x, xb, (int)n_x,
                                              W_qkv, wqkvb, (int)n_wqkv,
                                              W_proj, wprojb);

  // QKV: M=4096, N=3072, K=1024 — 768 blocks (3/CU)
  gemm128_kernel<<<dim3(3 * Cc / 128, Bb * Tt / 128), blk, 0, stream>>>(
      xb, wqkvb, b_qkv, Cc, q_ws, k_ws, v_ws);
  // attention: 512 balanced-pair blocks, 512 threads (8 waves) each
  attn_kernel<<<dim3(512), dim3(512), 0, stream>>>(q_ws, k_ws, v_ws, sinkp, y_ws);
  // proj: M=4096, N=1024, K=1024 — 64x64 tiles -> 1024 blocks (4/CU)
  gemm64_kernel<<<dim3(Cc / 64, Bb * Tt / 64), blk, 0, stream>>>(
      y_ws, wprojb, b_proj, Hh * Dd, out, Cc);
}

// Round 14
// 171.580 us; speedup vs baseline: 1.2815x; 1.0510x over previous
//
#include <hip/hip_runtime.h>
#include <hip/hip_bf16.h>

#define Bb 2
#define Tt 2048
#define Cc 1024
#define Hh 16
#define Dd 64

typedef __bf16 bf8 __attribute__((ext_vector_type(8)));
typedef __bf16 bf4 __attribute__((ext_vector_type(4)));
typedef float f4 __attribute__((ext_vector_type(4)));

typedef __attribute__((address_space(3))) void lds_void;
typedef const __attribute__((address_space(1))) void g_void;

__device__ __forceinline__ void gload_lds16(const __bf16* g, __bf16* l) {
  __builtin_amdgcn_global_load_lds((g_void*)g, (lds_void*)l, 16, 0, 0);
}

// exp2 that lowers directly to v_exp_f32 (hw exp is base-2)
__device__ __forceinline__ float ex2(float x) { return __builtin_amdgcn_exp2f(x); }

// fused fp32 -> bf16 convert for x, W_qkv, W_proj in one launch
__global__ __launch_bounds__(256) void cvt3_kernel(
    const float* __restrict__ a, __bf16* __restrict__ oa, int na,
    const float* __restrict__ b, __bf16* __restrict__ ob, int nb,
    const float* __restrict__ c, __bf16* __restrict__ oc) {
  int gi = blockIdx.x * 256 + threadIdx.x;
  const int t0 = na >> 3, t1 = t0 + (nb >> 3);
  const float* src; __bf16* dst; int idx;
  if (gi < t0)      { src = a; dst = oa; idx = gi; }
  else if (gi < t1) { src = b; dst = ob; idx = gi - t0; }
  else              { src = c; dst = oc; idx = gi - t1; }
  const float* p = src + (size_t)idx * 8;
  float4 u = *(const float4*)p;
  float4 v = *(const float4*)(p + 4);
  bf8 r;
  r[0] = (__bf16)u.x; r[1] = (__bf16)u.y; r[2] = (__bf16)u.z; r[3] = (__bf16)u.w;
  r[4] = (__bf16)v.x; r[5] = (__bf16)v.y; r[6] = (__bf16)v.z; r[7] = (__bf16)v.w;
  *(bf8*)(dst + (size_t)idx * 8) = r;
}

// QKV GEMM: anchor core + DOUBLE-BUFFERED staging (one barrier/iter: barrier
// drains DMA(k), stage(k+1) into the other buffer, compute(k) — each DMA gets
// a full compute window; halves barrier count vs anchor).  Epi v-transpose
// buffer UNIONS with the staging buffers (post-loop barrier) -> LDS 36 KB,
// 3 blocks/CU unchanged.  q pre-scaled 0.125*log2e; v written t-contiguous.
__global__ __launch_bounds__(256) void gemm128_kernel(
    const __bf16* __restrict__ A, const __bf16* __restrict__ W,
    const float* __restrict__ bias, int K,
    __bf16* __restrict__ q_ws, __bf16* __restrict__ k_ws,
    __bf16* __restrict__ v_ws)
{
  const int tid = threadIdx.x;
  const int lane = tid & 63, wave = tid >> 6;
  const int lr = lane & 15, lq = lane >> 4;
  const int m_blk = blockIdx.y * 128, n_blk = blockIdx.x * 128;
  const int wm = (wave & 1) * 64, wn = (wave >> 1) * 64;

  // union: [ As0 4K | As1 4K | Bs0 4K | Bs1 4K ] elems (32 KB) overlaid by
  // Epi[4][64*72] (36 KB) after the post-loop barrier.
  __shared__ __align__(16) __bf16 smem[4 * 64 * 72];
  __bf16* AsB = smem;             // AsB + bsel*4096
  __bf16* BsB = smem + 8192;      // BsB + bsel*4096

  const int srow = tid >> 2, scol = (tid & 3) * 8;
  const __bf16* ag0 = A + (size_t)(m_blk + srow) * K + scol;
  const __bf16* ag1 = A + (size_t)(m_blk + 64 + srow) * K + scol;
  const __bf16* bg0 = W + (size_t)(n_blk + srow) * K + scol;
  const __bf16* bg1 = W + (size_t)(n_blk + 64 + srow) * K + scol;

  auto stage = [&](int k0, int bsel) {
    __bf16* as = AsB + bsel * 4096;
    __bf16* bs = BsB + bsel * 4096;
    gload_lds16(ag0 + k0, as + tid * 8);
    gload_lds16(ag1 + k0, as + 2048 + tid * 8);
    gload_lds16(bg0 + k0, bs + tid * 8);
    gload_lds16(bg1 + k0, bs + 2048 + tid * 8);
  };

  f4 acc[4][4] = {};
  const int nk = K >> 5;

  stage(0, 0);
  for (int k = 0; k < nk; ++k) {
    __syncthreads();   // drains DMA(k); all waves done reading buf[k&1] (iter k-2)
    if (k + 1 < nk) stage((k + 1) * 32, (k + 1) & 1);

    const __bf16* As = AsB + (k & 1) * 4096;
    const __bf16* Bs = BsB + (k & 1) * 4096;
    bf8 af[4], bfr[4];
    #pragma unroll
    for (int i = 0; i < 4; ++i)
      af[i] = *(const bf8*)&As[(wm + i * 16 + lr) * 32 + lq * 8];
    #pragma unroll
    for (int j = 0; j < 4; ++j)
      bfr[j] = *(const bf8*)&Bs[(wn + j * 16 + lr) * 32 + lq * 8];
    #pragma unroll
    for (int i = 0; i < 4; ++i)
      #pragma unroll
      for (int j = 0; j < 4; ++j)
        acc[i][j] = __builtin_amdgcn_mfma_f32_16x16x32_bf16(af[i], bfr[j], acc[i][j], 0, 0, 0);
  }
  __syncthreads();   // staging dead; Epi may overlay it

  const int col0 = n_blk + wn;          // 64-aligned -> which/h wave-uniform
  const int which = col0 >> 10;
  const int b = m_blk >> 11;            // 128-row blocks never straddle b
  const int h = (col0 & 1023) >> 6;
  const size_t bh = (size_t)b * Hh + h;

  if (which == 2) {
    // v: transpose through per-wave LDS, write t-contiguous
    __bf16* E = smem + wave * 4608;     // 64*72 per wave
    #pragma unroll
    for (int j = 0; j < 4; ++j) {
      float bv = bias[col0 + j * 16 + lr];
      #pragma unroll
      for (int i = 0; i < 4; ++i)
        #pragma unroll
        for (int r = 0; r < 4; ++r)
          E[(j * 16 + lr) * 72 + i * 16 + lq * 4 + r] = (__bf16)(acc[i][j][r] + bv);
    }
    asm volatile("s_waitcnt lgkmcnt(0)" ::: "memory");  // wave-private RAW
    const int t0 = (m_blk + wm) & 2047;
    const int dd = lane >> 3, tl = (lane & 7) * 8;
    #pragma unroll
    for (int di = 0; di < 8; ++di) {
      int d = di * 8 + dd;
      bf8 vv = *(const bf8*)&E[d * 72 + tl];
      *(bf8*)&v_ws[(bh * Dd + d) * Tt + t0 + tl] = vv;
    }
  } else {
    __bf16* dst = (which == 0) ? q_ws : k_ws;
    const float scl = (which == 0) ? 0.18033688011112042f : 1.0f;  // 1/sqrt(D)*log2e
    #pragma unroll
    for (int i = 0; i < 4; ++i) {
      #pragma unroll
      for (int j = 0; j < 4; ++j) {
        #pragma unroll
        for (int r = 0; r < 4; ++r) {
          int row = m_blk + wm + i * 16 + lq * 4 + r;  // C/D: row = 4*quad + reg
          int col = col0 + j * 16 + lr;                // C/D: col = lane&15
          float val = (acc[i][j][r] + bias[col]) * scl;
          int d = col & 63, t = row & 2047;
          dst[(bh * Tt + t) * Dd + d] = (__bf16)val;
        }
      }
    }
  }
}

// Proj GEMM: 64x64 tiles -> 1024 blocks (4/CU TLP).  8 KB LDS, single-buffer.
__global__ __launch_bounds__(256) void gemm64_kernel(
    const __bf16* __restrict__ A, const __bf16* __restrict__ W,
    const float* __restrict__ bias, int K, float* __restrict__ out, int ldo)
{
  const int tid = threadIdx.x;
  const int lane = tid & 63, wave = tid >> 6;
  const int lr = lane & 15, lq = lane >> 4;
  const int m_blk = blockIdx.y * 64, n_blk = blockIdx.x * 64;
  const int wm = (wave & 1) * 32, wn = (wave >> 1) * 32;

  __shared__ __align__(16) __bf16 As[64 * 32];
  __shared__ __align__(16) __bf16 Bs[64 * 32];

  const int srow = tid >> 2, scol = (tid & 3) * 8;
  const __bf16* ag = A + (size_t)(m_blk + srow) * K + scol;
  const __bf16* bg = W + (size_t)(n_blk + srow) * K + scol;
  __bf16* al = As + tid * 8;
  __bf16* bl = Bs + tid * 8;

  f4 acc[2][2] = {};
  for (int k0 = 0; k0 < K; k0 += 32) {
    gload_lds16(ag + k0, al);
    gload_lds16(bg + k0, bl);
    __syncthreads();

    bf8 af[2], bfr[2];
    #pragma unroll
    for (int i = 0; i < 2; ++i)
      af[i] = *(const bf8*)&As[(wm + i * 16 + lr) * 32 + lq * 8];
    #pragma unroll
    for (int j = 0; j < 2; ++j)
      bfr[j] = *(const bf8*)&Bs[(wn + j * 16 + lr) * 32 + lq * 8];
    #pragma unroll
    for (int i = 0; i < 2; ++i)
      #pragma unroll
      for (int j = 0; j < 2; ++j)
        acc[i][j] = __builtin_amdgcn_mfma_f32_16x16x32_bf16(af[i], bfr[j], acc[i][j], 0, 0, 0);
    __syncthreads();
  }

  #pragma unroll
  for (int i = 0; i < 2; ++i)
    #pragma unroll
    for (int j = 0; j < 2; ++j)
      #pragma unroll
      for (int r = 0; r < 4; ++r) {
        int row = m_blk + wm + i * 16 + lq * 4 + r;
        int col = n_blk + wn + j * 16 + lr;
        out[(size_t)row * ldo + col] = acc[i][j][r] + bias[col];
      }
}

// Flash attention with sink, fixed softmax reference m=0, log2-domain scores.
// R14: 1024 blocks x 256 threads (4 waves x 16 q = 64 q/block), K/V double-
// buffered (40 KB LDS -> 4 blocks/CU; 4 independent barrier groups per CU
// interleave, the TLP overlap that drove R12->R13).  No S-prefetch (dbuf
// can't keep V(kt) live across stage(kt+2)).  Every wave needs every tile;
// diag mask only at kt==qt.  Balanced pairing: qt + qt' = 31.
__global__ __launch_bounds__(256) void attn_kernel(
    const __bf16* __restrict__ q_ws, const __bf16* __restrict__ k_ws,
    const __bf16* __restrict__ v_ws, const float* __restrict__ sink,
    __bf16* __restrict__ y_ws)
{
  int bi = blockIdx.x;
  int qt, bhi;
  if (bi < 512) { qt = 31 - (bi >> 5); bhi = bi & 31; }
  else          { qt = (bi - 512) >> 5; bhi = (bi - 512) & 31; }
  const int h = bhi & (Hh - 1);
  const int b = bhi >> 4;
  const int tid = threadIdx.x;
  const int lane = tid & 63, wave = tid >> 6;          // wave 0..3
  const int lr = lane & 15, lq = lane >> 4;

  __shared__ __align__(16) __bf16 KsU[2][64 * 64];     // swizzled [key][d], dbuf
  __shared__ __align__(16) __bf16 VtU[2][64 * 64];     // swizzled [d][key], dbuf
  __shared__ __align__(16) __bf16 PsU[4][16 * 64];     // per-wave [q][key]

  const __bf16* qp = q_ws + (size_t)bhi * Tt * Dd;
  const __bf16* kp = k_ws + (size_t)bhi * Tt * Dd;
  const __bf16* vp = v_ws + (size_t)bhi * Dd * Tt;     // [d][t]

  const int qbase = qt * 64;
  const int qlo = qbase + wave * 16;                   // wave's lowest q row

  // Q fragments: 16 rows/wave, loop-invariant registers
  bf8 qf[2];
  {
    const __bf16* qrow = qp + (size_t)(qlo + lr) * Dd;
    qf[0] = *(const bf8*)(qrow + lq * 8);
    qf[1] = *(const bf8*)(qrow + 32 + lq * 8);
  }

  float rs = 0.f;             // per-lane denominator partial (q = lr)
  f4 o_acc[4] = {};

  // staging: 256 threads, 2 K chunks + 2 V chunks each (64 rows x 8 slots)
  const int srow_lo = tid >> 3;         // 0..31
  const int sslot = tid & 7;
  const int nkt = qt + 1;

  auto stage = [&](int kt2, int bsel) {
    const int kbase2 = kt2 * 64;
    #pragma unroll
    for (int ii = 0; ii < 2; ++ii) {
      const int r = ii * 32 + srow_lo;
      const int cc = sslot ^ (r & 7);            // XOR granule swizzle
      gload_lds16(kp + (size_t)(kbase2 + r) * Dd + cc * 8,
                  &KsU[bsel][ii * 2048 + tid * 8]);
      gload_lds16(vp + (size_t)r * Tt + kbase2 + cc * 8,
                  &VtU[bsel][ii * 2048 + tid * 8]);
    }
  };

  stage(0, 0);
  for (int kt = 0; kt < nkt; ++kt) {
    __syncthreads();        // drains DMA(kt); readers of buf[kt&1] (iter kt-2) done
    if (kt + 1 < nkt) stage(kt + 1, (kt + 1) & 1);

    const __bf16* Kb = KsU[kt & 1];
    const __bf16* Vb = VtU[kt & 1];
    const int kbase = kt * 64;

    // S^T = K Q^T (A=K rows, B=Q rows): c[r] = S[key=kbase+nt*16+lq*4+r][q=qlo+lr]
    f4 s[4];
    #pragma unroll
    for (int nt = 0; nt < 4; ++nt) {
      const int krow = nt * 16 + lr;
      const int x7 = krow & 7;
      bf8 kb0 = *(const bf8*)&Kb[krow * 64 + ((lq ^ x7) * 8)];
      bf8 kb1 = *(const bf8*)&Kb[krow * 64 + (((4 + lq) ^ x7) * 8)];
      f4 c = {};
      c = __builtin_amdgcn_mfma_f32_16x16x32_bf16(kb0, qf[0], c, 0, 0, 0);
      c = __builtin_amdgcn_mfma_f32_16x16x32_bf16(kb1, qf[1], c, 0, 0, 0);
      s[nt] = c;
    }

    __bf16* Pw = PsU[wave];
    if (kt == qt) {         // diagonal tile (only one per wave at 64-q blocks)
      #pragma unroll
      for (int nt = 0; nt < 4; ++nt) {
        const int qg = qlo + lr;
        const int kg = kbase + nt * 16 + lq * 4;
        bf4 pb;
        #pragma unroll
        for (int r = 0; r < 4; ++r) {
          float sv = (kg + r > qg) ? -1e30f : s[nt][r];
          float p = ex2(sv);              // scores already in log2 domain
          rs += p;
          pb[r] = (__bf16)p;
        }
        const int G = (nt * 2 + (lq >> 1)) ^ (lr & 7);
        *(bf4*)&Pw[lr * 64 + G * 8 + (lq & 1) * 4] = pb;
      }
    } else {
      #pragma unroll
      for (int nt = 0; nt < 4; ++nt) {
        bf4 pb;
        #pragma unroll
        for (int r = 0; r < 4; ++r) {
          float p = ex2(s[nt][r]);
          rs += p;
          pb[r] = (__bf16)p;
        }
        const int G = (nt * 2 + (lq >> 1)) ^ (lr & 7);
        *(bf4*)&Pw[lr * 64 + G * 8 + (lq & 1) * 4] = pb;
      }
    }
    asm volatile("s_waitcnt lgkmcnt(0)" ::: "memory");  // wave-private RAW on Pw

    // O += P @ V
    #pragma unroll
    for (int ks = 0; ks < 2; ++ks) {
      const int pg = ((ks * 4 + lq) ^ (lr & 7)) * 8;
      bf8 pa = *(const bf8*)&Pw[lr * 64 + pg];
      #pragma unroll
      for (int dt = 0; dt < 4; ++dt) {
        const int vrow = dt * 16 + lr;
        bf8 vb = *(const bf8*)&Vb[vrow * 64 + (((ks * 4 + lq) ^ (vrow & 7)) * 8)];
        o_acc[dt] = __builtin_amdgcn_mfma_f32_16x16x32_bf16(pa, vb, o_acc[dt], 0, 0, 0);
      }
    }
  }

  // denominator: reduce per-lane partials over lq (lanes sharing lr)
  rs += __shfl_xor(rs, 16, 64);
  rs += __shfl_xor(rs, 32, 64);
  const float snk = ex2(sink[h] * 1.44269504f);   // e^sink
  float inv = 1.0f / (rs + snk);
  // redistribute: O rows are q = lq*4+r; denom lives at lane with lr == lq*4+r
  float invr[4];
  #pragma unroll
  for (int r = 0; r < 4; ++r)
    invr[r] = __shfl(inv, lq * 4 + r, 64);

  #pragma unroll
  for (int dt = 0; dt < 4; ++dt)
    #pragma unroll
    for (int r = 0; r < 4; ++r) {
      int qrow = qlo + lq * 4 + r;
      y_ws[((size_t)b * Tt + qrow) * Cc + h * Dd + dt * 16 + lr] =
          (__bf16)(o_acc[dt][r] * invr[r]);
    }
}

extern "C" void kernel_launch(void* const* d_in, const int* in_sizes, int n_in,
                              void* d_out, int out_size, void* d_ws, size_t ws_size,
                              hipStream_t stream) {
  const float* x      = (const float*)d_in[0];
  const float* W_qkv  = (const float*)d_in[1];
  const float* b_qkv  = (const float*)d_in[2];
  const float* W_proj = (const float*)d_in[3];
  const float* b_proj = (const float*)d_in[4];
  const float* sinkp  = (const float*)d_in[5];
  float* out = (float*)d_out;

  const size_t n_x    = (size_t)Bb * Tt * Cc;        // 4.19M
  const size_t n_wqkv = (size_t)3 * Hh * Dd * Cc;    // 3.15M
  const size_t n_wprj = (size_t)Cc * Hh * Dd;        // 1.05M
  const size_t nqkv   = (size_t)Bb * Hh * Tt * Dd;   // 4.19M

  __bf16* xb     = (__bf16*)d_ws;          // also aliased as y_ws after QKV GEMM
  __bf16* wqkvb  = xb + n_x;
  __bf16* wprojb = wqkvb + n_wqkv;
  __bf16* q_ws   = wprojb + n_wprj;
  __bf16* k_ws   = q_ws + nqkv;
  __bf16* v_ws   = k_ws + nqkv;
  __bf16* y_ws   = xb;                     // lifetime-disjoint alias

  dim3 blk(256);
  const int cvt_blocks = (int)((n_x + n_wqkv + n_wprj) / 8 / 256);  // 4096
  cvt3_kernel<<<cvt_blocks, blk, 0, stream>>>(x, xb, (int)n_x,
                                              W_qkv, wqkvb, (int)n_wqkv,
                                              W_proj, wprojb);

  // QKV: M=4096, N=3072, K=1024 — 768 blocks (3/CU), dbuf
  gemm128_kernel<<<dim3(3 * Cc / 128, Bb * Tt / 128), blk, 0, stream>>>(
      xb, wqkvb, b_qkv, Cc, q_ws, k_ws, v_ws);
  // attention: 1024 balanced-pair blocks, 256 threads, 4 blocks/CU
  attn_kernel<<<dim3(1024), blk, 0, stream>>>(q_ws, k_ws, v_ws, sinkp, y_ws);
  // proj: M=4096, N=1024, K=1024 — 64x64 tiles -> 1024 blocks (4/CU)
  gemm64_kernel<<<dim3(Cc / 64, Bb * Tt / 64), blk, 0, stream>>>(
      y_ws, wprojb, b_proj, Hh * Dd, out, Cc);
}